// Round 5
// baseline (2337.450 us; speedup 1.0000x reference)
//
#include <hip/hip_runtime.h>
#include <cstdint>
#include <cstddef>

// ---------------- problem constants ----------------
#define NN 30000        // nodes
#define NE 400000       // edges per scatter set
#define EG (NE + NN)    // GAT edges incl self loops
#define NSETS 5
#define NCLS 10
#define BN_EPS 1e-5f
#define NBK 59          // destination buckets of 512 nodes (30000 >> 9 = 58)

typedef __bf16 bf16x8 __attribute__((ext_vector_type(8)));
typedef float  f32x4  __attribute__((ext_vector_type(4)));

// ---------------- workspace layout (bytes) ----------------
// U1:   xb [N][512]bf16 (dead after LIN gemm) / xcur5 [5][N][128]bf16
// GOUT: CSR staging (18 MB) -> tmp4 [4][N][128]bf16 -> gout [N][512]bf16 per branch
// AGG:  agg [N][512]bf16 (head-major), per branch
constexpr size_t alg(size_t x) { return (x + 255) & ~size_t(255); }
constexpr size_t OFF_U1    = 0;
constexpr size_t OFF_HB    = OFF_U1   + alg((size_t)5 * NN * 128 * 2);
constexpr size_t OFF_X2    = OFF_HB   + alg((size_t)NN * 128 * 2);
constexpr size_t OFF_AGG   = OFF_X2   + alg((size_t)NN * 128 * 4);
constexpr size_t OFF_GOUT  = OFF_AGG  + alg((size_t)NN * 512 * 2);
constexpr size_t OFF_WT    = OFF_GOUT + alg((size_t)NN * 512 * 2);
constexpr size_t OFF_WATT  = OFF_WT   + alg((size_t)11 * 65536 * 2);
constexpr size_t OFF_OFF6  = OFF_WATT + alg((size_t)5 * 2 * 4 * 128 * 4);
constexpr size_t OFF_SPP   = OFF_OFF6 + alg((size_t)6 * (NN + 1) * 4);
constexpr size_t OFF_GSRC  = OFF_SPP  + alg((size_t)NSETS * NE * 8);
constexpr size_t OFF_CNT   = OFF_GSRC + alg((size_t)EG * 4);
constexpr size_t OFF_BCUR  = OFF_CNT  + alg((size_t)12 * NN * 4);
constexpr size_t OFF_AS5   = OFF_BCUR + alg((size_t)6 * 64 * 4);
constexpr size_t OFF_AD5   = OFF_AS5  + alg((size_t)5 * NN * 4 * 4);
constexpr size_t WS_NEED   = OFF_AD5  + alg((size_t)5 * NN * 4 * 4);   // ~149 MB

// ---------------- helpers ----------------
__device__ __forceinline__ float lrelu02(float v) { return v > 0.f ? v : 0.2f * v; }
__device__ __forceinline__ float eluf(float v)    { return v > 0.f ? v : __expf(v) - 1.f; }
__device__ __forceinline__ float bf2f(unsigned u) {
    union { unsigned i; float f; } c; c.i = u << 16; return c.f;
}
__device__ __forceinline__ unsigned short f2bf(float f) {
    union { float f; unsigned i; } c; c.f = f;
    unsigned u = c.i + 0x7FFFu + ((c.i >> 16) & 1u);
    return (unsigned short)(u >> 16);
}
__device__ __forceinline__ void gload_lds16(const void* g, void* l) {
    __builtin_amdgcn_global_load_lds(
        (const __attribute__((address_space(1))) void*)(uintptr_t)g,
        (__attribute__((address_space(3))) void*)(unsigned)(uintptr_t)l,
        16, 0, 0);
}

// ---------------- CSR build ----------------
__global__ void count_all(const int* __restrict__ scat_idx, const int* __restrict__ edge_ix,
                          int* __restrict__ cnt6) {
    const int total = NSETS * NE + EG;
    for (int i = blockIdx.x * blockDim.x + threadIdx.x; i < total; i += gridDim.x * blockDim.x) {
        if (i < NSETS * NE) {
            int s = i / NE, e = i - s * NE;
            atomicAdd(&cnt6[s * NN + scat_idx[(size_t)s * 2 * NE + NE + e]], 1);
        } else {
            int j = i - NSETS * NE;
            int d = (j < NE) ? edge_ix[NE + j] : (j - NE);
            atomicAdd(&cnt6[5 * NN + d], 1);
        }
    }
}

__global__ void exscan30k(const int* __restrict__ cnt6, int* __restrict__ off6) {
    const int* cnt = cnt6 + blockIdx.x * NN;
    int* off = off6 + blockIdx.x * (NN + 1);
    constexpr int per = 30;
    __shared__ int s[1024];
    const int t = threadIdx.x;
    const int base0 = t * per;
    int sum = 0;
    #pragma unroll
    for (int i = 0; i < per; ++i) { int idx = base0 + i; sum += (idx < NN) ? cnt[idx] : 0; }
    s[t] = sum;
    __syncthreads();
    for (int d = 1; d < 1024; d <<= 1) {
        int v = (t >= d) ? s[t - d] : 0;
        __syncthreads();
        s[t] += v;
        __syncthreads();
    }
    int run = s[t] - sum;
    #pragma unroll
    for (int i = 0; i < per; ++i) {
        int idx = base0 + i;
        if (idx < NN) { off[idx] = run; run += cnt[idx]; }
    }
    if (t == 1023) off[NN] = s[1023];
}

// bucket cursors start at CSR base of each 512-node bucket
__global__ void init_bcur(const int* __restrict__ off6, int* __restrict__ bcur) {
    int t = threadIdx.x;
    if (t < 6 * NBK) {
        int g = t / NBK, b = t - g * NBK;
        bcur[g * 64 + b] = off6[g * (NN + 1) + b * 512];
    }
}

// pass A: append edges into bucket-dense staging (coords == final CSR coords)
__global__ void binA(const int* __restrict__ scat_idx, const float* __restrict__ scat_w,
                     const int* __restrict__ edge_ix, int* __restrict__ bcur,
                     int2* __restrict__ stg_sp, int* __restrict__ stg_g) {
    const int total = NSETS * NE + EG;
    for (int i = blockIdx.x * blockDim.x + threadIdx.x; i < total; i += gridDim.x * blockDim.x) {
        if (i < NSETS * NE) {
            int g = i / NE, e = i - g * NE;
            int src = scat_idx[(size_t)g * 2 * NE + e];
            int d   = scat_idx[(size_t)g * 2 * NE + NE + e];
            float w = scat_w[(size_t)g * NE + e];
            int pos = atomicAdd(&bcur[g * 64 + (d >> 9)], 1);
            int2 pk; pk.x = src | (d << 15); pk.y = __float_as_int(w);
            stg_sp[(size_t)g * NE + pos] = pk;
        } else {
            int j = i - NSETS * NE;
            int src, d;
            if (j < NE) { src = edge_ix[j]; d = edge_ix[NE + j]; }
            else        { src = j - NE;     d = src; }
            int pos = atomicAdd(&bcur[5 * 64 + (d >> 9)], 1);
            stg_g[pos] = src | (d << 15);
        }
    }
}

// pass B: sequential read of staging, L2-local scatter within ~50KB bucket slices
__global__ void binB(const int2* __restrict__ stg_sp, const int* __restrict__ stg_g,
                     const int* __restrict__ off6, int* __restrict__ cur6,
                     int2* __restrict__ spp, int* __restrict__ g_src) {
    const int total = NSETS * NE + EG;
    for (int i = blockIdx.x * blockDim.x + threadIdx.x; i < total; i += gridDim.x * blockDim.x) {
        if (i < NSETS * NE) {
            int g = i / NE, e = i - g * NE;
            int2 pk = stg_sp[(size_t)g * NE + e];
            int src = pk.x & 0x7fff, d = (pk.x >> 15) & 0x7fff;
            int p = off6[g * (NN + 1) + d] + atomicAdd(&cur6[g * NN + d], 1);
            int2 o; o.x = src; o.y = pk.y;
            spp[(size_t)g * NE + p] = o;
        } else {
            int j = i - NSETS * NE;
            int w0 = stg_g[j];
            int src = w0 & 0x7fff, d = (w0 >> 15) & 0x7fff;
            int p = off6[5 * (NN + 1) + d] + atomicAdd(&cur6[5 * NN + d], 1);
            g_src[p] = src;
        }
    }
}

// ---------------- conversions ----------------
__global__ void convx(const float* __restrict__ x, unsigned short* __restrict__ xb) {
    const int total = NN * 512 / 4;
    for (int i = blockIdx.x * blockDim.x + threadIdx.x; i < total; i += gridDim.x * blockDim.x) {
        float4 v = *(const float4*)(x + (size_t)i * 4);
        ushort4 o;
        o.x = f2bf(v.x); o.y = f2bf(v.y); o.z = f2bf(v.z); o.w = f2bf(v.w);
        *(ushort4*)(xb + (size_t)i * 4) = o;
    }
}

// W [B][K][N] f32 -> WT [B][N][K] bf16
__global__ void transW(const float* __restrict__ W, unsigned short* __restrict__ WT,
                       int Kd, int Nd, int B) {
    const int total = B * Kd * Nd;
    for (int i = blockIdx.x * blockDim.x + threadIdx.x; i < total; i += gridDim.x * blockDim.x) {
        int b = i / (Kd * Nd);
        int r = i - b * Kd * Nd;
        int n = r / Kd, k = r - n * Kd;
        WT[i] = f2bf(W[(size_t)b * Kd * Nd + (size_t)k * Nd + n]);
    }
}

// watt[i][t][h][k] = sum_c gat_W[i][k][h*128+c] * att_{t}[i][h][c]   (all f32)
__global__ void wattk(const float* __restrict__ gat_W, const float* __restrict__ att_src,
                      const float* __restrict__ att_dst, float* __restrict__ watt) {
    int tid = blockIdx.x * blockDim.x + threadIdx.x;
    if (tid >= 5120) return;
    int k = tid & 127, h = (tid >> 7) & 3, t = (tid >> 9) & 1, i = tid >> 10;
    const float* att = (t == 0 ? att_src : att_dst) + ((size_t)i * 4 + h) * 128;
    const float* Wr  = gat_W + ((size_t)i * 128 + k) * 512 + h * 128;
    float s = 0.f;
    #pragma unroll 8
    for (int c = 0; c < 128; ++c) s = fmaf(Wr[c], att[c], s);
    watt[tid] = s;
}

// ---------------- MFMA bf16 GEMM: C[M][NC] = A[M][K] @ BT[NC][K]^T ----------------
template<int ROWS>
__device__ __forceinline__ void stage64(const unsigned short* __restrict__ src, int ld,
                                        int row0, int maxrow, int k0, char* lds, int t) {
    const int wave = t >> 6, lane = t & 63;
    const int sub = lane >> 3;
    const int kch = (lane & 7) ^ sub;
    for (int j = wave; j < ROWS / 8; j += 4) {
        int grow = row0 + j * 8 + sub;
        if (grow > maxrow) grow = maxrow;
        gload_lds16(src + (size_t)grow * ld + k0 + kch * 8, lds + j * 1024);
    }
}

#define GM_LIN 0     // outb = bf16(A@B + bias); x2 = f32(same)
#define GM_MLP 2     // x2 += BN(A@B + bias)
#define GM_GATELU 3  // block-diag: A col-offset by bn; outb = bf16(elu(A@B + bias))

template<int K, int NC, int MODE>
__global__ void __launch_bounds__(256) mgemm(const unsigned short* __restrict__ A,
                                             const unsigned short* __restrict__ BT,
                                             const float* __restrict__ bias,
                                             unsigned short* __restrict__ outb,
                                             float* __restrict__ x2,
                                             const float* __restrict__ bng, const float* __restrict__ bnb,
                                             const float* __restrict__ bnm, const float* __restrict__ bnv,
                                             int M) {
    __shared__ __align__(16) char As[64 * 128];
    __shared__ __align__(16) char Bs[128 * 128];
    const int t = threadIdx.x, wave = t >> 6, lane = t & 63;
    const int bm = blockIdx.x * 64, bn = blockIdx.y * 128;
    const int wr = (wave >> 1) * 32, wc = (wave & 1) * 64;
    const int l15 = lane & 15, l4 = lane >> 4;
    const int rsw = (l15 & 7) << 4;
    const int lda   = (MODE == GM_GATELU) ? 512 : K;
    const int kbase = (MODE == GM_GATELU) ? bn : 0;
    f32x4 acc[2][4] = {};

    for (int kt = 0; kt < K; kt += 64) {
        stage64<64>(A, lda, bm, M - 1, kbase + kt, As, t);
        stage64<128>(BT, K, bn, NC - 1, kt, Bs, t);
        __syncthreads();
        #pragma unroll
        for (int kk = 0; kk < 2; ++kk) {
            bf16x8 af[2], bf[4];
            const int koff = kk * 64 + l4 * 16;
            #pragma unroll
            for (int fm = 0; fm < 2; ++fm) {
                int r = wr + fm * 16 + l15;
                af[fm] = *(const bf16x8*)(As + r * 128 + (koff ^ rsw));
            }
            #pragma unroll
            for (int fn = 0; fn < 4; ++fn) {
                int c = wc + fn * 16 + l15;
                bf[fn] = *(const bf16x8*)(Bs + c * 128 + (koff ^ rsw));
            }
            #pragma unroll
            for (int fm = 0; fm < 2; ++fm)
                #pragma unroll
                for (int fn = 0; fn < 4; ++fn)
                    acc[fm][fn] = __builtin_amdgcn_mfma_f32_16x16x32_bf16(af[fm], bf[fn], acc[fm][fn], 0, 0, 0);
        }
        __syncthreads();
    }

    #pragma unroll
    for (int fn = 0; fn < 4; ++fn) {
        const int c = bn + wc + fn * 16 + l15;
        float bias_c = 0.f, sc = 0.f, sh = 0.f;
        if constexpr (MODE == GM_LIN || MODE == GM_GATELU) bias_c = bias[c];
        if constexpr (MODE == GM_MLP) {
            bias_c = bias[c];
            sc = bng[c] * rsqrtf(bnv[c] + BN_EPS);
            sh = bnb[c] - bnm[c] * sc;
        }
        #pragma unroll
        for (int fm = 0; fm < 2; ++fm) {
            #pragma unroll
            for (int rg = 0; rg < 4; ++rg) {
                int r = bm + wr + fm * 16 + l4 * 4 + rg;
                if (r < M) {
                    float v = acc[fm][fn][rg];
                    if constexpr (MODE == GM_LIN) {
                        v += bias_c;
                        outb[(size_t)r * NC + c] = f2bf(v);
                        x2[(size_t)r * NC + c] = v;
                    } else if constexpr (MODE == GM_GATELU) {
                        outb[(size_t)r * NC + c] = f2bf(eluf(v + bias_c));
                    } else {
                        x2[(size_t)r * NC + c] += (v + bias_c) * sc + sh;
                    }
                }
            }
        }
    }
}

// ---------------- phase 0: tmp_y = abs(sp(y+1, hb)), 4-way edge unroll ----------------
__global__ void __launch_bounds__(256) sp_abs4(const int* __restrict__ off6,
                                               const int2* __restrict__ spp,
                                               const unsigned short* __restrict__ hb,
                                               unsigned short* __restrict__ tmp4) {
    const int y = blockIdx.y;
    const int* off = off6 + (y + 1) * (NN + 1);
    const int2* pk = spp + (size_t)(y + 1) * NE;
    unsigned short* out = tmp4 + (size_t)y * NN * 128;

    const int wid  = blockIdx.x * 4 + (threadIdx.x >> 6);
    const int lane = threadIdx.x & 63;
    const int co   = lane * 2;
    const int s0 = off[wid], s1 = off[wid + 1];
    float a0 = 0.f, a1 = 0.f;
    int j = s0;
    for (; j + 3 < s1; j += 4) {
        int2 e0 = pk[j], e1 = pk[j + 1], e2 = pk[j + 2], e3 = pk[j + 3];
        unsigned v0 = *(const unsigned*)(hb + (size_t)e0.x * 128 + co);
        unsigned v1 = *(const unsigned*)(hb + (size_t)e1.x * 128 + co);
        unsigned v2 = *(const unsigned*)(hb + (size_t)e2.x * 128 + co);
        unsigned v3 = *(const unsigned*)(hb + (size_t)e3.x * 128 + co);
        float w0 = __int_as_float(e0.y), w1 = __int_as_float(e1.y);
        float w2 = __int_as_float(e2.y), w3 = __int_as_float(e3.y);
        a0 = fmaf(w0, bf2f(v0 & 0xffffu), a0); a1 = fmaf(w0, bf2f(v0 >> 16), a1);
        a0 = fmaf(w1, bf2f(v1 & 0xffffu), a0); a1 = fmaf(w1, bf2f(v1 >> 16), a1);
        a0 = fmaf(w2, bf2f(v2 & 0xffffu), a0); a1 = fmaf(w2, bf2f(v2 >> 16), a1);
        a0 = fmaf(w3, bf2f(v3 & 0xffffu), a0); a1 = fmaf(w3, bf2f(v3 >> 16), a1);
    }
    for (; j < s1; ++j) {
        int2 e = pk[j];
        float wj = __int_as_float(e.y);
        unsigned v = *(const unsigned*)(hb + (size_t)e.x * 128 + co);
        a0 = fmaf(wj, bf2f(v & 0xffffu), a0);
        a1 = fmaf(wj, bf2f(v >> 16), a1);
    }
    a0 = fabsf(a0); a1 = fabsf(a1);
    unsigned o = (unsigned)f2bf(a0) | ((unsigned)f2bf(a1) << 16);
    *(unsigned*)(out + (size_t)wid * 128 + co) = o;
}

// ---------------- phase 1: xcur_y = sp(0, {hb,tmp0..3}) fused + attention scores ----------------
__global__ void __launch_bounds__(256) sp_fused5(const int* __restrict__ off0,
                                                 const int2* __restrict__ spp0,
                                                 const unsigned short* __restrict__ hb,
                                                 const unsigned short* __restrict__ tmp4,
                                                 unsigned short* __restrict__ xcur5,
                                                 const float* __restrict__ watt,
                                                 float* __restrict__ as5,
                                                 float* __restrict__ ad5) {
    __shared__ float sWatt[5120];           // [5][2][4][128]
    for (int i = threadIdx.x; i < 5120; i += 256) sWatt[i] = watt[i];
    __syncthreads();

    const int wid  = blockIdx.x * 4 + (threadIdx.x >> 6);
    const int lane = threadIdx.x & 63;
    const int co   = lane * 2;
    const int s0 = off0[wid], s1 = off0[wid + 1];
    const unsigned short* t0 = tmp4;
    const unsigned short* t1 = tmp4 + (size_t)1 * NN * 128;
    const unsigned short* t2 = tmp4 + (size_t)2 * NN * 128;
    const unsigned short* t3 = tmp4 + (size_t)3 * NN * 128;

    float a[5][2] = {};
    int j = s0;
    for (; j + 1 < s1; j += 2) {
        int2 eA = spp0[j], eB = spp0[j + 1];
        size_t rA = (size_t)eA.x * 128 + co, rB = (size_t)eB.x * 128 + co;
        unsigned vA0 = *(const unsigned*)(hb + rA), vB0 = *(const unsigned*)(hb + rB);
        unsigned vA1 = *(const unsigned*)(t0 + rA), vB1 = *(const unsigned*)(t0 + rB);
        unsigned vA2 = *(const unsigned*)(t1 + rA), vB2 = *(const unsigned*)(t1 + rB);
        unsigned vA3 = *(const unsigned*)(t2 + rA), vB3 = *(const unsigned*)(t2 + rB);
        unsigned vA4 = *(const unsigned*)(t3 + rA), vB4 = *(const unsigned*)(t3 + rB);
        float wA = __int_as_float(eA.y), wB = __int_as_float(eB.y);
        a[0][0] = fmaf(wA, bf2f(vA0 & 0xffffu), a[0][0]); a[0][1] = fmaf(wA, bf2f(vA0 >> 16), a[0][1]);
        a[1][0] = fmaf(wA, bf2f(vA1 & 0xffffu), a[1][0]); a[1][1] = fmaf(wA, bf2f(vA1 >> 16), a[1][1]);
        a[2][0] = fmaf(wA, bf2f(vA2 & 0xffffu), a[2][0]); a[2][1] = fmaf(wA, bf2f(vA2 >> 16), a[2][1]);
        a[3][0] = fmaf(wA, bf2f(vA3 & 0xffffu), a[3][0]); a[3][1] = fmaf(wA, bf2f(vA3 >> 16), a[3][1]);
        a[4][0] = fmaf(wA, bf2f(vA4 & 0xffffu), a[4][0]); a[4][1] = fmaf(wA, bf2f(vA4 >> 16), a[4][1]);
        a[0][0] = fmaf(wB, bf2f(vB0 & 0xffffu), a[0][0]); a[0][1] = fmaf(wB, bf2f(vB0 >> 16), a[0][1]);
        a[1][0] = fmaf(wB, bf2f(vB1 & 0xffffu), a[1][0]); a[1][1] = fmaf(wB, bf2f(vB1 >> 16), a[1][1]);
        a[2][0] = fmaf(wB, bf2f(vB2 & 0xffffu), a[2][0]); a[2][1] = fmaf(wB, bf2f(vB2 >> 16), a[2][1]);
        a[3][0] = fmaf(wB, bf2f(vB3 & 0xffffu), a[3][0]); a[3][1] = fmaf(wB, bf2f(vB3 >> 16), a[3][1]);
        a[4][0] = fmaf(wB, bf2f(vB4 & 0xffffu), a[4][0]); a[4][1] = fmaf(wB, bf2f(vB4 >> 16), a[4][1]);
    }
    if (j < s1) {
        int2 e = spp0[j];
        size_t r = (size_t)e.x * 128 + co;
        unsigned v0 = *(const unsigned*)(hb + r);
        unsigned v1 = *(const unsigned*)(t0 + r);
        unsigned v2 = *(const unsigned*)(t1 + r);
        unsigned v3 = *(const unsigned*)(t2 + r);
        unsigned v4 = *(const unsigned*)(t3 + r);
        float wj = __int_as_float(e.y);
        a[0][0] = fmaf(wj, bf2f(v0 & 0xffffu), a[0][0]); a[0][1] = fmaf(wj, bf2f(v0 >> 16), a[0][1]);
        a[1][0] = fmaf(wj, bf2f(v1 & 0xffffu), a[1][0]); a[1][1] = fmaf(wj, bf2f(v1 >> 16), a[1][1]);
        a[2][0] = fmaf(wj, bf2f(v2 & 0xffffu), a[2][0]); a[2][1] = fmaf(wj, bf2f(v2 >> 16), a[2][1]);
        a[3][0] = fmaf(wj, bf2f(v3 & 0xffffu), a[3][0]); a[3][1] = fmaf(wj, bf2f(v3 >> 16), a[3][1]);
        a[4][0] = fmaf(wj, bf2f(v4 & 0xffffu), a[4][0]); a[4][1] = fmaf(wj, bf2f(v4 >> 16), a[4][1]);
    }
    #pragma unroll
    for (int y = 0; y < 5; ++y) {
        unsigned o = (unsigned)f2bf(a[y][0]) | ((unsigned)f2bf(a[y][1]) << 16);
        *(unsigned*)(xcur5 + (size_t)y * NN * 128 + (size_t)wid * 128 + co) = o;
    }

    // attention scores for all 5 sets: as5/ad5[i][n][h] = xcur_i[n] . watt[i][s/d][h]
    #pragma unroll
    for (int i = 0; i < 5; ++i) {
        #pragma unroll
        for (int h = 0; h < 4; ++h) {
            const float* wS = sWatt + ((i * 2 + 0) * 4 + h) * 128;
            const float* wD = sWatt + ((i * 2 + 1) * 4 + h) * 128;
            float ps = a[i][0] * wS[co] + a[i][1] * wS[co + 1];
            float pd = a[i][0] * wD[co] + a[i][1] * wD[co + 1];
            #pragma unroll
            for (int dd = 1; dd < 64; dd <<= 1) { ps += __shfl_xor(ps, dd); pd += __shfl_xor(pd, dd); }
            if (lane == 0) {
                as5[(size_t)i * NN * 4 + (size_t)wid * 4 + h] = ps;
                ad5[(size_t)i * NN * 4 + (size_t)wid * 4 + h] = pd;
            }
        }
    }
}

// ---------------- GAT aggregation on xcur (pre-W): agg[n][h*128+c] = sum alpha_h * xcur[src][c] ----------------
__device__ __forceinline__ void acc8(float* a, float al, uint4 v) {
    a[0] = fmaf(al, bf2f(v.x & 0xffffu), a[0]); a[1] = fmaf(al, bf2f(v.x >> 16), a[1]);
    a[2] = fmaf(al, bf2f(v.y & 0xffffu), a[2]); a[3] = fmaf(al, bf2f(v.y >> 16), a[3]);
    a[4] = fmaf(al, bf2f(v.z & 0xffffu), a[4]); a[5] = fmaf(al, bf2f(v.z >> 16), a[5]);
    a[6] = fmaf(al, bf2f(v.w & 0xffffu), a[6]); a[7] = fmaf(al, bf2f(v.w >> 16), a[7]);
}

__global__ void __launch_bounds__(256) gat_agg2(const int* __restrict__ goff, const int* __restrict__ gsrc,
                                                const float* __restrict__ as_, const float* __restrict__ ad_,
                                                const unsigned short* __restrict__ xcur,
                                                unsigned short* __restrict__ agg) {
    const int wid  = blockIdx.x * 4 + (threadIdx.x >> 6);
    const int lane = threadIdx.x & 63;
    const int hd   = lane >> 4;                  // head
    const int cl   = (lane & 15) * 8;            // 8 channels of xcur row
    const int s0 = goff[wid], s1 = goff[wid + 1];
    const float4 adv4 = *(const float4*)(ad_ + (size_t)wid * 4);

    // phase 1: online max + exp-sum per head
    float m[4] = {-1e30f, -1e30f, -1e30f, -1e30f};
    float s[4] = {0.f, 0.f, 0.f, 0.f};
    for (int j = s0 + lane; j < s1; j += 64) {
        const int si = gsrc[j];
        float4 av = *(const float4*)(as_ + (size_t)si * 4);
        float e[4] = {lrelu02(av.x + adv4.x), lrelu02(av.y + adv4.y),
                      lrelu02(av.z + adv4.z), lrelu02(av.w + adv4.w)};
        #pragma unroll
        for (int h = 0; h < 4; ++h) {
            if (e[h] > m[h]) { s[h] = s[h] * __expf(m[h] - e[h]) + 1.f; m[h] = e[h]; }
            else             { s[h] += __expf(e[h] - m[h]); }
        }
    }
    #pragma unroll
    for (int d = 1; d < 64; d <<= 1) {
        #pragma unroll
        for (int h = 0; h < 4; ++h) {
            float om = __shfl_xor(m[h], d);
            float os = __shfl_xor(s[h], d);
            float nm = fmaxf(m[h], om);
            s[h] = s[h] * __expf(m[h] - nm) + os * __expf(om - nm);
            m[h] = nm;
        }
    }
    const float advh = hd == 0 ? adv4.x : hd == 1 ? adv4.y : hd == 2 ? adv4.z : adv4.w;
    const float mv   = hd == 0 ? m[0]   : hd == 1 ? m[1]   : hd == 2 ? m[2]   : m[3];
    const float dv   = hd == 0 ? s[0]   : hd == 1 ? s[1]   : hd == 2 ? s[2]   : s[3];
    const float inv  = 1.f / (dv + 1e-16f);

    // phase 2: alpha-weighted xcur aggregation (each lane: its head, its 8 channels)
    float ac[8] = {};
    int j = s0;
    for (; j + 1 < s1; j += 2) {
        int i0 = gsrc[j], i1 = gsrc[j + 1];
        float q0 = as_[(size_t)i0 * 4 + hd], q1 = as_[(size_t)i1 * 4 + hd];
        uint4 v0 = *(const uint4*)(xcur + (size_t)i0 * 128 + cl);
        uint4 v1 = *(const uint4*)(xcur + (size_t)i1 * 128 + cl);
        float al0 = __expf(lrelu02(q0 + advh) - mv) * inv;
        float al1 = __expf(lrelu02(q1 + advh) - mv) * inv;
        acc8(ac, al0, v0); acc8(ac, al1, v1);
    }
    if (j < s1) {
        int si = gsrc[j];
        float q = as_[(size_t)si * 4 + hd];
        uint4 v = *(const uint4*)(xcur + (size_t)si * 128 + cl);
        float al = __expf(lrelu02(q + advh) - mv) * inv;
        acc8(ac, al, v);
    }
    uint4 ov;
    ov.x = (unsigned)f2bf(ac[0]) | ((unsigned)f2bf(ac[1]) << 16);
    ov.y = (unsigned)f2bf(ac[2]) | ((unsigned)f2bf(ac[3]) << 16);
    ov.z = (unsigned)f2bf(ac[4]) | ((unsigned)f2bf(ac[5]) << 16);
    ov.w = (unsigned)f2bf(ac[6]) | ((unsigned)f2bf(ac[7]) << 16);
    *(uint4*)(agg + (size_t)wid * 512 + hd * 128 + cl) = ov;
}

// ---------------- final: out = log_softmax( elu(bn0(x2)) @ outW + outb ) ----------------
__global__ void __launch_bounds__(256) final_out(const float* __restrict__ x2,
                                                 const float* __restrict__ bn0g, const float* __restrict__ bn0b,
                                                 const float* __restrict__ bn0m, const float* __restrict__ bn0v,
                                                 const float* __restrict__ outW, const float* __restrict__ outb,
                                                 float* __restrict__ out) {
    __shared__ float sW[128 * 12];
    __shared__ float sSc[128], sSh[128];
    for (int i = threadIdx.x; i < 1280; i += 256) {
        int r = i / 10, c = i - r * 10;
        sW[r * 12 + c] = outW[i];
    }
    if (threadIdx.x < 128) {
        int c = threadIdx.x;
        float sc = bn0g[c] * rsqrtf(bn0v[c] + BN_EPS);
        sSc[c] = sc;
        sSh[c] = bn0b[c] - bn0m[c] * sc;
    }
    __syncthreads();
    const int wid  = blockIdx.x * 4 + (threadIdx.x >> 6);
    const int lane = threadIdx.x & 63;
    const int c0 = lane * 2;
    float2 a = *(const float2*)(x2 + (size_t)wid * 128 + c0);
    float a0 = eluf(a.x * sSc[c0] + sSh[c0]);
    float a1 = eluf(a.y * sSc[c0 + 1] + sSh[c0 + 1]);
    float p[NCLS];
    #pragma unroll
    for (int j = 0; j < NCLS; ++j)
        p[j] = a0 * sW[c0 * 12 + j] + a1 * sW[(c0 + 1) * 12 + j];
    #pragma unroll
    for (int j = 0; j < NCLS; ++j) {
        float v = p[j];
        v += __shfl_xor(v, 1);  v += __shfl_xor(v, 2);  v += __shfl_xor(v, 4);
        v += __shfl_xor(v, 8);  v += __shfl_xor(v, 16); v += __shfl_xor(v, 32);
        p[j] = v;
    }
    float z[NCLS];
    #pragma unroll
    for (int j = 0; j < NCLS; ++j) z[j] = p[j] + outb[j];
    float m = z[0];
    #pragma unroll
    for (int j = 1; j < NCLS; ++j) m = fmaxf(m, z[j]);
    float ssum = 0.f;
    #pragma unroll
    for (int j = 0; j < NCLS; ++j) ssum += __expf(z[j] - m);
    float lse = m + __logf(ssum);
    #pragma unroll
    for (int j = 0; j < NCLS; ++j)
        if (lane == j) out[(size_t)wid * NCLS + j] = z[j] - lse;
}

// ---------------- launcher ----------------
extern "C" void kernel_launch(void* const* d_in, const int* in_sizes, int n_in,
                              void* d_out, int out_size, void* d_ws, size_t ws_size,
                              hipStream_t stream) {
    const float* x        = (const float*)d_in[0];
    const int*   edge_ix  = (const int*)  d_in[1];
    const int*   scat_idx = (const int*)  d_in[2];
    const float* scat_w   = (const float*)d_in[3];
    const float* lin_W    = (const float*)d_in[4];
    const float* lin_b    = (const float*)d_in[5];
    const float* gat_W    = (const float*)d_in[6];
    const float* att_src  = (const float*)d_in[7];
    const float* att_dst  = (const float*)d_in[8];
    const float* gat_b    = (const float*)d_in[9];
    const float* mlp_W    = (const float*)d_in[10];
    const float* mlp_b    = (const float*)d_in[11];
    const float* bn_g     = (const float*)d_in[12];
    const float* bn_b     = (const float*)d_in[13];
    const float* bn_m     = (const float*)d_in[14];
    const float* bn_v     = (const float*)d_in[15];
    const float* bn0_g    = (const float*)d_in[16];
    const float* bn0_b    = (const float*)d_in[17];
    const float* bn0_m    = (const float*)d_in[18];
    const float* bn0_v    = (const float*)d_in[19];
    const float* out_W    = (const float*)d_in[20];
    const float* out_b    = (const float*)d_in[21];
    float* out = (float*)d_out;

    char* ws = (char*)d_ws;
    unsigned short* xb    = (unsigned short*)(ws + OFF_U1);
    unsigned short* xcur5 = (unsigned short*)(ws + OFF_U1);
    unsigned short* hb    = (unsigned short*)(ws + OFF_HB);
    float*          x2    = (float*)(ws + OFF_X2);
    unsigned short* agg   = (unsigned short*)(ws + OFF_AGG);
    unsigned short* gout  = (unsigned short*)(ws + OFF_GOUT);
    unsigned short* tmp4  = (unsigned short*)(ws + OFF_GOUT);
    int2*  stg_sp = (int2*)(ws + OFF_GOUT);                          // CSR staging (dead before tmp4)
    int*   stg_g  = (int*)(ws + OFF_GOUT + (size_t)NSETS * NE * 8);
    unsigned short* wt    = (unsigned short*)(ws + OFF_WT);
    unsigned short* linWT = wt;
    unsigned short* gatWT = wt + 65536;
    unsigned short* mlpWT = wt + 65536 * 6;
    float* watt   = (float*)(ws + OFF_WATT);
    int*   off6   = (int*)(ws + OFF_OFF6);
    int2*  spp    = (int2*)(ws + OFF_SPP);
    int*   g_src  = (int*)(ws + OFF_GSRC);
    int*   cnt6   = (int*)(ws + OFF_CNT);
    int*   cur6   = cnt6 + 6 * NN;
    int*   bcur   = (int*)(ws + OFF_BCUR);
    float* as5    = (float*)(ws + OFF_AS5);
    float* ad5    = (float*)(ws + OFF_AD5);

    const dim3 b256(256);

    // ---- CSR build: count -> scan -> bucket-append -> L2-local scatter ----
    hipMemsetAsync(cnt6, 0, (size_t)12 * NN * 4, stream);
    count_all<<<2048, b256, 0, stream>>>(scat_idx, edge_ix, cnt6);
    exscan30k<<<6, 1024, 0, stream>>>(cnt6, off6);
    init_bcur<<<1, 384, 0, stream>>>(off6, bcur);
    binA<<<2048, b256, 0, stream>>>(scat_idx, scat_w, edge_ix, bcur, stg_sp, stg_g);
    binB<<<2048, b256, 0, stream>>>(stg_sp, stg_g, off6, cur6, spp, g_src);

    // ---- dtype conversions + W@att precompute ----
    convx<<<2048, b256, 0, stream>>>(x, xb);
    transW<<<256, b256, 0, stream>>>(lin_W, linWT, 512, 128, 1);
    transW<<<640, b256, 0, stream>>>(gat_W, gatWT, 128, 512, 5);
    transW<<<640, b256, 0, stream>>>(mlp_W, mlpWT, 512, 128, 5);
    wattk<<<20, b256, 0, stream>>>(gat_W, att_src, att_dst, watt);

    // ---- h = x @ lin_W + lin_b (bf16 out) ; x2 = h (f32) ----
    mgemm<512, 128, GM_LIN><<<dim3(469, 1), b256, 0, stream>>>(
        xb, linWT, lin_b, hb, x2, nullptr, nullptr, nullptr, nullptr, NN);

    // ---- solo passes (+ fused attention scores for all 5 sets) ----
    sp_abs4<<<dim3(7500, 4), b256, 0, stream>>>(off6, spp, hb, tmp4);
    sp_fused5<<<7500, b256, 0, stream>>>(off6, spp, hb, tmp4, xcur5, watt, as5, ad5);

    // ---- 5 GAT branches: aggregate-then-multiply ----
    for (int i = 0; i < NSETS; ++i) {
        gat_agg2<<<7500, b256, 0, stream>>>(off6 + 5 * (NN + 1), g_src,
                                            as5 + (size_t)i * NN * 4, ad5 + (size_t)i * NN * 4,
                                            xcur5 + (size_t)i * NN * 128, agg);
        mgemm<128, 512, GM_GATELU><<<dim3(469, 4), b256, 0, stream>>>(
            agg, gatWT + (size_t)i * 65536, gat_b + (size_t)i * 512, gout, nullptr,
            nullptr, nullptr, nullptr, nullptr, NN);
        mgemm<512, 128, GM_MLP><<<dim3(469, 1), b256, 0, stream>>>(
            gout, mlpWT + (size_t)i * 65536, mlp_b + (size_t)i * 128, nullptr, x2,
            bn_g + (size_t)i * 128, bn_b + (size_t)i * 128,
            bn_m + (size_t)i * 128, bn_v + (size_t)i * 128, NN);
    }

    // ---- final ----
    final_out<<<7500, b256, 0, stream>>>(x2, bn0_g, bn0_b, bn0_m, bn0_v, out_W, out_b, out);
}

// Round 6
// 1003.794 us; speedup vs baseline: 2.3286x; 2.3286x over previous
//
#include <hip/hip_runtime.h>
#include <cstdint>
#include <cstddef>

// ---------------- problem constants ----------------
#define NN 30000        // nodes
#define NE 400000       // edges per scatter set
#define EG (NE + NN)    // GAT edges incl self loops
#define NSETS 5
#define NCLS 10
#define BN_EPS 1e-5f

typedef __bf16 bf16x8 __attribute__((ext_vector_type(8)));
typedef float  f32x4  __attribute__((ext_vector_type(4)));

// ---------------- workspace layout (bytes) ----------------
// U1:   xb [N][512]bf16 (dead after LIN gemm) / xcur5 [5][N][128]bf16
// GOUT: tmp4 [4][N][128]bf16 (dead after sp_fused5) -> gout [N][512]bf16 per branch
constexpr size_t alg(size_t x) { return (x + 255) & ~size_t(255); }
constexpr size_t OFF_U1    = 0;
constexpr size_t OFF_HB    = OFF_U1   + alg((size_t)5 * NN * 128 * 2);
constexpr size_t OFF_X2    = OFF_HB   + alg((size_t)NN * 128 * 2);
constexpr size_t OFF_AGG   = OFF_X2   + alg((size_t)NN * 128 * 4);
constexpr size_t OFF_GOUT  = OFF_AGG  + alg((size_t)NN * 512 * 2);
constexpr size_t OFF_WT    = OFF_GOUT + alg((size_t)NN * 512 * 2);
constexpr size_t OFF_WATT  = OFF_WT   + alg((size_t)11 * 65536 * 2);
constexpr size_t OFF_OFF6  = OFF_WATT + alg((size_t)5 * 2 * 4 * 128 * 4);
constexpr size_t OFF_SPP   = OFF_OFF6 + alg((size_t)6 * (NN + 1) * 4);
constexpr size_t OFF_GSRC  = OFF_SPP  + alg((size_t)NSETS * NE * 8);
constexpr size_t OFF_CNT   = OFF_GSRC + alg((size_t)EG * 4);
constexpr size_t OFF_AS5   = OFF_CNT  + alg((size_t)12 * NN * 4);
constexpr size_t OFF_AD5   = OFF_AS5  + alg((size_t)5 * NN * 4 * 4);
constexpr size_t WS_NEED   = OFF_AD5  + alg((size_t)5 * NN * 4 * 4);   // ~149 MB

// ---------------- helpers ----------------
__device__ __forceinline__ float lrelu02(float v) { return v > 0.f ? v : 0.2f * v; }
__device__ __forceinline__ float eluf(float v)    { return v > 0.f ? v : __expf(v) - 1.f; }
__device__ __forceinline__ float bf2f(unsigned u) {
    union { unsigned i; float f; } c; c.i = u << 16; return c.f;
}
__device__ __forceinline__ unsigned short f2bf(float f) {
    union { float f; unsigned i; } c; c.f = f;
    unsigned u = c.i + 0x7FFFu + ((c.i >> 16) & 1u);
    return (unsigned short)(u >> 16);
}
__device__ __forceinline__ void gload_lds16(const void* g, void* l) {
    __builtin_amdgcn_global_load_lds(
        (const __attribute__((address_space(1))) void*)(uintptr_t)g,
        (__attribute__((address_space(3))) void*)(unsigned)(uintptr_t)l,
        16, 0, 0);
}

// ---------------- CSR build (fused over 5 sets + GAT graph) ----------------
// NOTE (round 5 lesson): atomic scatter cost is governed by CONTENTION, not write
// locality. Per-node cursors (30k/graph, ~14 hits each) = 145 us; 59 bucket
// cursors (6.9k hits each) serialized to 1.55 ms. Keep per-node cursors.
__global__ void count_all(const int* __restrict__ scat_idx, const int* __restrict__ edge_ix,
                          int* __restrict__ cnt6) {
    const int total = NSETS * NE + EG;
    for (int i = blockIdx.x * blockDim.x + threadIdx.x; i < total; i += gridDim.x * blockDim.x) {
        if (i < NSETS * NE) {
            int s = i / NE, e = i - s * NE;
            atomicAdd(&cnt6[s * NN + scat_idx[(size_t)s * 2 * NE + NE + e]], 1);
        } else {
            int j = i - NSETS * NE;
            int d = (j < NE) ? edge_ix[NE + j] : (j - NE);
            atomicAdd(&cnt6[5 * NN + d], 1);
        }
    }
}

__global__ void exscan30k(const int* __restrict__ cnt6, int* __restrict__ off6) {
    const int* cnt = cnt6 + blockIdx.x * NN;
    int* off = off6 + blockIdx.x * (NN + 1);
    constexpr int per = 30;
    __shared__ int s[1024];
    const int t = threadIdx.x;
    const int base0 = t * per;
    int sum = 0;
    #pragma unroll
    for (int i = 0; i < per; ++i) { int idx = base0 + i; sum += (idx < NN) ? cnt[idx] : 0; }
    s[t] = sum;
    __syncthreads();
    for (int d = 1; d < 1024; d <<= 1) {
        int v = (t >= d) ? s[t - d] : 0;
        __syncthreads();
        s[t] += v;
        __syncthreads();
    }
    int run = s[t] - sum;
    #pragma unroll
    for (int i = 0; i < per; ++i) {
        int idx = base0 + i;
        if (idx < NN) { off[idx] = run; run += cnt[idx]; }
    }
    if (t == 1023) off[NN] = s[1023];
}

__global__ void fill_all(const int* __restrict__ scat_idx, const float* __restrict__ scat_w,
                         const int* __restrict__ edge_ix, const int* __restrict__ off6,
                         int* __restrict__ cur6, int2* __restrict__ spp,
                         int* __restrict__ g_src) {
    const int total = NSETS * NE + EG;
    for (int i = blockIdx.x * blockDim.x + threadIdx.x; i < total; i += gridDim.x * blockDim.x) {
        if (i < NSETS * NE) {
            int s = i / NE, e = i - s * NE;
            int d = scat_idx[(size_t)s * 2 * NE + NE + e];
            int p = off6[s * (NN + 1) + d] + atomicAdd(&cur6[s * NN + d], 1);
            int2 pk;
            pk.x = scat_idx[(size_t)s * 2 * NE + e];
            pk.y = __float_as_int(scat_w[(size_t)s * NE + e]);
            spp[(size_t)s * NE + p] = pk;
        } else {
            int j = i - NSETS * NE;
            int sidx, d;
            if (j < NE) { sidx = edge_ix[j]; d = edge_ix[NE + j]; }
            else        { sidx = j - NE;     d = sidx; }
            int p = off6[5 * (NN + 1) + d] + atomicAdd(&cur6[5 * NN + d], 1);
            g_src[p] = sidx;
        }
    }
}

// ---------------- conversions ----------------
__global__ void convx(const float* __restrict__ x, unsigned short* __restrict__ xb) {
    const int total = NN * 512 / 4;
    for (int i = blockIdx.x * blockDim.x + threadIdx.x; i < total; i += gridDim.x * blockDim.x) {
        float4 v = *(const float4*)(x + (size_t)i * 4);
        ushort4 o;
        o.x = f2bf(v.x); o.y = f2bf(v.y); o.z = f2bf(v.z); o.w = f2bf(v.w);
        *(ushort4*)(xb + (size_t)i * 4) = o;
    }
}

// W [B][K][N] f32 -> WT [B][N][K] bf16
__global__ void transW(const float* __restrict__ W, unsigned short* __restrict__ WT,
                       int Kd, int Nd, int B) {
    const int total = B * Kd * Nd;
    for (int i = blockIdx.x * blockDim.x + threadIdx.x; i < total; i += gridDim.x * blockDim.x) {
        int b = i / (Kd * Nd);
        int r = i - b * Kd * Nd;
        int n = r / Kd, k = r - n * Kd;
        WT[i] = f2bf(W[(size_t)b * Kd * Nd + (size_t)k * Nd + n]);
    }
}

// watt[i][t][h][k] = sum_c gat_W[i][k][h*128+c] * att_{t}[i][h][c]   (all f32)
__global__ void wattk(const float* __restrict__ gat_W, const float* __restrict__ att_src,
                      const float* __restrict__ att_dst, float* __restrict__ watt) {
    int tid = blockIdx.x * blockDim.x + threadIdx.x;
    if (tid >= 5120) return;
    int k = tid & 127, h = (tid >> 7) & 3, t = (tid >> 9) & 1, i = tid >> 10;
    const float* att = (t == 0 ? att_src : att_dst) + ((size_t)i * 4 + h) * 128;
    const float* Wr  = gat_W + ((size_t)i * 128 + k) * 512 + h * 128;
    float s = 0.f;
    #pragma unroll 8
    for (int c = 0; c < 128; ++c) s = fmaf(Wr[c], att[c], s);
    watt[tid] = s;
}

// ---------------- MFMA bf16 GEMM: C[M][NC] = A[M][K] @ BT[NC][K]^T ----------------
template<int ROWS>
__device__ __forceinline__ void stage64(const unsigned short* __restrict__ src, int ld,
                                        int row0, int maxrow, int k0, char* lds, int t) {
    const int wave = t >> 6, lane = t & 63;
    const int sub = lane >> 3;
    const int kch = (lane & 7) ^ sub;
    for (int j = wave; j < ROWS / 8; j += 4) {
        int grow = row0 + j * 8 + sub;
        if (grow > maxrow) grow = maxrow;
        gload_lds16(src + (size_t)grow * ld + k0 + kch * 8, lds + j * 1024);
    }
}

#define GM_LIN 0     // outb = bf16(A@B + bias); x2 = f32(same)
#define GM_MLP 2     // x2 += BN(A@B + bias)
#define GM_GATELU 3  // block-diag: A col-offset by bn; outb = bf16(elu(A@B + bias))

template<int K, int NC, int MODE>
__global__ void __launch_bounds__(256) mgemm(const unsigned short* __restrict__ A,
                                             const unsigned short* __restrict__ BT,
                                             const float* __restrict__ bias,
                                             unsigned short* __restrict__ outb,
                                             float* __restrict__ x2,
                                             const float* __restrict__ bng, const float* __restrict__ bnb,
                                             const float* __restrict__ bnm, const float* __restrict__ bnv,
                                             int M) {
    __shared__ __align__(16) char As[64 * 128];
    __shared__ __align__(16) char Bs[128 * 128];
    const int t = threadIdx.x, wave = t >> 6, lane = t & 63;
    const int bm = blockIdx.x * 64, bn = blockIdx.y * 128;
    const int wr = (wave >> 1) * 32, wc = (wave & 1) * 64;
    const int l15 = lane & 15, l4 = lane >> 4;
    const int rsw = (l15 & 7) << 4;
    const int lda   = (MODE == GM_GATELU) ? 512 : K;
    const int kbase = (MODE == GM_GATELU) ? bn : 0;
    f32x4 acc[2][4] = {};

    for (int kt = 0; kt < K; kt += 64) {
        stage64<64>(A, lda, bm, M - 1, kbase + kt, As, t);
        stage64<128>(BT, K, bn, NC - 1, kt, Bs, t);
        __syncthreads();
        #pragma unroll
        for (int kk = 0; kk < 2; ++kk) {
            bf16x8 af[2], bf[4];
            const int koff = kk * 64 + l4 * 16;
            #pragma unroll
            for (int fm = 0; fm < 2; ++fm) {
                int r = wr + fm * 16 + l15;
                af[fm] = *(const bf16x8*)(As + r * 128 + (koff ^ rsw));
            }
            #pragma unroll
            for (int fn = 0; fn < 4; ++fn) {
                int c = wc + fn * 16 + l15;
                bf[fn] = *(const bf16x8*)(Bs + c * 128 + (koff ^ rsw));
            }
            #pragma unroll
            for (int fm = 0; fm < 2; ++fm)
                #pragma unroll
                for (int fn = 0; fn < 4; ++fn)
                    acc[fm][fn] = __builtin_amdgcn_mfma_f32_16x16x32_bf16(af[fm], bf[fn], acc[fm][fn], 0, 0, 0);
        }
        __syncthreads();
    }

    #pragma unroll
    for (int fn = 0; fn < 4; ++fn) {
        const int c = bn + wc + fn * 16 + l15;
        float bias_c = 0.f, sc = 0.f, sh = 0.f;
        if constexpr (MODE == GM_LIN || MODE == GM_GATELU) bias_c = bias[c];
        if constexpr (MODE == GM_MLP) {
            bias_c = bias[c];
            sc = bng[c] * rsqrtf(bnv[c] + BN_EPS);
            sh = bnb[c] - bnm[c] * sc;
        }
        #pragma unroll
        for (int fm = 0; fm < 2; ++fm) {
            #pragma unroll
            for (int rg = 0; rg < 4; ++rg) {
                int r = bm + wr + fm * 16 + l4 * 4 + rg;
                if (r < M) {
                    float v = acc[fm][fn][rg];
                    if constexpr (MODE == GM_LIN) {
                        v += bias_c;
                        outb[(size_t)r * NC + c] = f2bf(v);
                        x2[(size_t)r * NC + c] = v;
                    } else if constexpr (MODE == GM_GATELU) {
                        outb[(size_t)r * NC + c] = f2bf(eluf(v + bias_c));
                    } else {
                        x2[(size_t)r * NC + c] += (v + bias_c) * sc + sh;
                    }
                }
            }
        }
    }
}

// ---------------- phase 0: tmp_y = abs(sp(y+1, hb)), 4-way edge unroll ----------------
__global__ void __launch_bounds__(256) sp_abs4(const int* __restrict__ off6,
                                               const int2* __restrict__ spp,
                                               const unsigned short* __restrict__ hb,
                                               unsigned short* __restrict__ tmp4) {
    const int y = blockIdx.y;
    const int* off = off6 + (y + 1) * (NN + 1);
    const int2* pk = spp + (size_t)(y + 1) * NE;
    unsigned short* out = tmp4 + (size_t)y * NN * 128;

    const int wid  = blockIdx.x * 4 + (threadIdx.x >> 6);
    const int lane = threadIdx.x & 63;
    const int co   = lane * 2;
    const int s0 = off[wid], s1 = off[wid + 1];
    float a0 = 0.f, a1 = 0.f;
    int j = s0;
    for (; j + 3 < s1; j += 4) {
        int2 e0 = pk[j], e1 = pk[j + 1], e2 = pk[j + 2], e3 = pk[j + 3];
        unsigned v0 = *(const unsigned*)(hb + (size_t)e0.x * 128 + co);
        unsigned v1 = *(const unsigned*)(hb + (size_t)e1.x * 128 + co);
        unsigned v2 = *(const unsigned*)(hb + (size_t)e2.x * 128 + co);
        unsigned v3 = *(const unsigned*)(hb + (size_t)e3.x * 128 + co);
        float w0 = __int_as_float(e0.y), w1 = __int_as_float(e1.y);
        float w2 = __int_as_float(e2.y), w3 = __int_as_float(e3.y);
        a0 = fmaf(w0, bf2f(v0 & 0xffffu), a0); a1 = fmaf(w0, bf2f(v0 >> 16), a1);
        a0 = fmaf(w1, bf2f(v1 & 0xffffu), a0); a1 = fmaf(w1, bf2f(v1 >> 16), a1);
        a0 = fmaf(w2, bf2f(v2 & 0xffffu), a0); a1 = fmaf(w2, bf2f(v2 >> 16), a1);
        a0 = fmaf(w3, bf2f(v3 & 0xffffu), a0); a1 = fmaf(w3, bf2f(v3 >> 16), a1);
    }
    for (; j < s1; ++j) {
        int2 e = pk[j];
        float wj = __int_as_float(e.y);
        unsigned v = *(const unsigned*)(hb + (size_t)e.x * 128 + co);
        a0 = fmaf(wj, bf2f(v & 0xffffu), a0);
        a1 = fmaf(wj, bf2f(v >> 16), a1);
    }
    a0 = fabsf(a0); a1 = fabsf(a1);
    unsigned o = (unsigned)f2bf(a0) | ((unsigned)f2bf(a1) << 16);
    *(unsigned*)(out + (size_t)wid * 128 + co) = o;
}

// ---------------- phase 1: xcur_y = sp(0, {hb,tmp0..3}) fused + attention scores ----------------
__global__ void __launch_bounds__(256) sp_fused5(const int* __restrict__ off0,
                                                 const int2* __restrict__ spp0,
                                                 const unsigned short* __restrict__ hb,
                                                 const unsigned short* __restrict__ tmp4,
                                                 unsigned short* __restrict__ xcur5,
                                                 const float* __restrict__ watt,
                                                 float* __restrict__ as5,
                                                 float* __restrict__ ad5) {
    __shared__ float sWatt[5120];           // [5][2][4][128]
    for (int i = threadIdx.x; i < 5120; i += 256) sWatt[i] = watt[i];
    __syncthreads();

    const int wid  = blockIdx.x * 4 + (threadIdx.x >> 6);
    const int lane = threadIdx.x & 63;
    const int co   = lane * 2;
    const int s0 = off0[wid], s1 = off0[wid + 1];
    const unsigned short* t0 = tmp4;
    const unsigned short* t1 = tmp4 + (size_t)1 * NN * 128;
    const unsigned short* t2 = tmp4 + (size_t)2 * NN * 128;
    const unsigned short* t3 = tmp4 + (size_t)3 * NN * 128;

    float a[5][2] = {};
    int j = s0;
    for (; j + 1 < s1; j += 2) {
        int2 eA = spp0[j], eB = spp0[j + 1];
        size_t rA = (size_t)eA.x * 128 + co, rB = (size_t)eB.x * 128 + co;
        unsigned vA0 = *(const unsigned*)(hb + rA), vB0 = *(const unsigned*)(hb + rB);
        unsigned vA1 = *(const unsigned*)(t0 + rA), vB1 = *(const unsigned*)(t0 + rB);
        unsigned vA2 = *(const unsigned*)(t1 + rA), vB2 = *(const unsigned*)(t1 + rB);
        unsigned vA3 = *(const unsigned*)(t2 + rA), vB3 = *(const unsigned*)(t2 + rB);
        unsigned vA4 = *(const unsigned*)(t3 + rA), vB4 = *(const unsigned*)(t3 + rB);
        float wA = __int_as_float(eA.y), wB = __int_as_float(eB.y);
        a[0][0] = fmaf(wA, bf2f(vA0 & 0xffffu), a[0][0]); a[0][1] = fmaf(wA, bf2f(vA0 >> 16), a[0][1]);
        a[1][0] = fmaf(wA, bf2f(vA1 & 0xffffu), a[1][0]); a[1][1] = fmaf(wA, bf2f(vA1 >> 16), a[1][1]);
        a[2][0] = fmaf(wA, bf2f(vA2 & 0xffffu), a[2][0]); a[2][1] = fmaf(wA, bf2f(vA2 >> 16), a[2][1]);
        a[3][0] = fmaf(wA, bf2f(vA3 & 0xffffu), a[3][0]); a[3][1] = fmaf(wA, bf2f(vA3 >> 16), a[3][1]);
        a[4][0] = fmaf(wA, bf2f(vA4 & 0xffffu), a[4][0]); a[4][1] = fmaf(wA, bf2f(vA4 >> 16), a[4][1]);
        a[0][0] = fmaf(wB, bf2f(vB0 & 0xffffu), a[0][0]); a[0][1] = fmaf(wB, bf2f(vB0 >> 16), a[0][1]);
        a[1][0] = fmaf(wB, bf2f(vB1 & 0xffffu), a[1][0]); a[1][1] = fmaf(wB, bf2f(vB1 >> 16), a[1][1]);
        a[2][0] = fmaf(wB, bf2f(vB2 & 0xffffu), a[2][0]); a[2][1] = fmaf(wB, bf2f(vB2 >> 16), a[2][1]);
        a[3][0] = fmaf(wB, bf2f(vB3 & 0xffffu), a[3][0]); a[3][1] = fmaf(wB, bf2f(vB3 >> 16), a[3][1]);
        a[4][0] = fmaf(wB, bf2f(vB4 & 0xffffu), a[4][0]); a[4][1] = fmaf(wB, bf2f(vB4 >> 16), a[4][1]);
    }
    if (j < s1) {
        int2 e = spp0[j];
        size_t r = (size_t)e.x * 128 + co;
        unsigned v0 = *(const unsigned*)(hb + r);
        unsigned v1 = *(const unsigned*)(t0 + r);
        unsigned v2 = *(const unsigned*)(t1 + r);
        unsigned v3 = *(const unsigned*)(t2 + r);
        unsigned v4 = *(const unsigned*)(t3 + r);
        float wj = __int_as_float(e.y);
        a[0][0] = fmaf(wj, bf2f(v0 & 0xffffu), a[0][0]); a[0][1] = fmaf(wj, bf2f(v0 >> 16), a[0][1]);
        a[1][0] = fmaf(wj, bf2f(v1 & 0xffffu), a[1][0]); a[1][1] = fmaf(wj, bf2f(v1 >> 16), a[1][1]);
        a[2][0] = fmaf(wj, bf2f(v2 & 0xffffu), a[2][0]); a[2][1] = fmaf(wj, bf2f(v2 >> 16), a[2][1]);
        a[3][0] = fmaf(wj, bf2f(v3 & 0xffffu), a[3][0]); a[3][1] = fmaf(wj, bf2f(v3 >> 16), a[3][1]);
        a[4][0] = fmaf(wj, bf2f(v4 & 0xffffu), a[4][0]); a[4][1] = fmaf(wj, bf2f(v4 >> 16), a[4][1]);
    }
    #pragma unroll
    for (int y = 0; y < 5; ++y) {
        unsigned o = (unsigned)f2bf(a[y][0]) | ((unsigned)f2bf(a[y][1]) << 16);
        *(unsigned*)(xcur5 + (size_t)y * NN * 128 + (size_t)wid * 128 + co) = o;
    }

    // attention scores for all 5 sets: as5/ad5[i][n][h] = xcur_i[n] . watt[i][s/d][h]
    #pragma unroll
    for (int i = 0; i < 5; ++i) {
        #pragma unroll
        for (int h = 0; h < 4; ++h) {
            const float* wS = sWatt + ((i * 2 + 0) * 4 + h) * 128;
            const float* wD = sWatt + ((i * 2 + 1) * 4 + h) * 128;
            float ps = a[i][0] * wS[co] + a[i][1] * wS[co + 1];
            float pd = a[i][0] * wD[co] + a[i][1] * wD[co + 1];
            #pragma unroll
            for (int dd = 1; dd < 64; dd <<= 1) { ps += __shfl_xor(ps, dd); pd += __shfl_xor(pd, dd); }
            if (lane == 0) {
                as5[(size_t)i * NN * 4 + (size_t)wid * 4 + h] = ps;
                ad5[(size_t)i * NN * 4 + (size_t)wid * 4 + h] = pd;
            }
        }
    }
}

// ---------------- GAT aggregation on xcur (pre-W): agg[n][h*128+c] = sum alpha_h * xcur[src][c] ----------------
__device__ __forceinline__ void acc8(float* a, float al, uint4 v) {
    a[0] = fmaf(al, bf2f(v.x & 0xffffu), a[0]); a[1] = fmaf(al, bf2f(v.x >> 16), a[1]);
    a[2] = fmaf(al, bf2f(v.y & 0xffffu), a[2]); a[3] = fmaf(al, bf2f(v.y >> 16), a[3]);
    a[4] = fmaf(al, bf2f(v.z & 0xffffu), a[4]); a[5] = fmaf(al, bf2f(v.z >> 16), a[5]);
    a[6] = fmaf(al, bf2f(v.w & 0xffffu), a[6]); a[7] = fmaf(al, bf2f(v.w >> 16), a[7]);
}

__global__ void __launch_bounds__(256) gat_agg2(const int* __restrict__ goff, const int* __restrict__ gsrc,
                                                const float* __restrict__ as_, const float* __restrict__ ad_,
                                                const unsigned short* __restrict__ xcur,
                                                unsigned short* __restrict__ agg) {
    const int wid  = blockIdx.x * 4 + (threadIdx.x >> 6);
    const int lane = threadIdx.x & 63;
    const int hd   = lane >> 4;                  // head
    const int cl   = (lane & 15) * 8;            // 8 channels of xcur row
    const int s0 = goff[wid], s1 = goff[wid + 1];
    const float4 adv4 = *(const float4*)(ad_ + (size_t)wid * 4);

    // phase 1: online max + exp-sum per head
    float m[4] = {-1e30f, -1e30f, -1e30f, -1e30f};
    float s[4] = {0.f, 0.f, 0.f, 0.f};
    for (int j = s0 + lane; j < s1; j += 64) {
        const int si = gsrc[j];
        float4 av = *(const float4*)(as_ + (size_t)si * 4);
        float e[4] = {lrelu02(av.x + adv4.x), lrelu02(av.y + adv4.y),
                      lrelu02(av.z + adv4.z), lrelu02(av.w + adv4.w)};
        #pragma unroll
        for (int h = 0; h < 4; ++h) {
            if (e[h] > m[h]) { s[h] = s[h] * __expf(m[h] - e[h]) + 1.f; m[h] = e[h]; }
            else             { s[h] += __expf(e[h] - m[h]); }
        }
    }
    #pragma unroll
    for (int d = 1; d < 64; d <<= 1) {
        #pragma unroll
        for (int h = 0; h < 4; ++h) {
            float om = __shfl_xor(m[h], d);
            float os = __shfl_xor(s[h], d);
            float nm = fmaxf(m[h], om);
            s[h] = s[h] * __expf(m[h] - nm) + os * __expf(om - nm);
            m[h] = nm;
        }
    }
    const float advh = hd == 0 ? adv4.x : hd == 1 ? adv4.y : hd == 2 ? adv4.z : adv4.w;
    const float mv   = hd == 0 ? m[0]   : hd == 1 ? m[1]   : hd == 2 ? m[2]   : m[3];
    const float dv   = hd == 0 ? s[0]   : hd == 1 ? s[1]   : hd == 2 ? s[2]   : s[3];
    const float inv  = 1.f / (dv + 1e-16f);

    // phase 2: alpha-weighted xcur aggregation (each lane: its head, its 8 channels)
    float ac[8] = {};
    int j = s0;
    for (; j + 1 < s1; j += 2) {
        int i0 = gsrc[j], i1 = gsrc[j + 1];
        float q0 = as_[(size_t)i0 * 4 + hd], q1 = as_[(size_t)i1 * 4 + hd];
        uint4 v0 = *(const uint4*)(xcur + (size_t)i0 * 128 + cl);
        uint4 v1 = *(const uint4*)(xcur + (size_t)i1 * 128 + cl);
        float al0 = __expf(lrelu02(q0 + advh) - mv) * inv;
        float al1 = __expf(lrelu02(q1 + advh) - mv) * inv;
        acc8(ac, al0, v0); acc8(ac, al1, v1);
    }
    if (j < s1) {
        int si = gsrc[j];
        float q = as_[(size_t)si * 4 + hd];
        uint4 v = *(const uint4*)(xcur + (size_t)si * 128 + cl);
        float al = __expf(lrelu02(q + advh) - mv) * inv;
        acc8(ac, al, v);
    }
    uint4 ov;
    ov.x = (unsigned)f2bf(ac[0]) | ((unsigned)f2bf(ac[1]) << 16);
    ov.y = (unsigned)f2bf(ac[2]) | ((unsigned)f2bf(ac[3]) << 16);
    ov.z = (unsigned)f2bf(ac[4]) | ((unsigned)f2bf(ac[5]) << 16);
    ov.w = (unsigned)f2bf(ac[6]) | ((unsigned)f2bf(ac[7]) << 16);
    *(uint4*)(agg + (size_t)wid * 512 + hd * 128 + cl) = ov;
}

// ---------------- final: out = log_softmax( elu(bn0(x2)) @ outW + outb ) ----------------
__global__ void __launch_bounds__(256) final_out(const float* __restrict__ x2,
                                                 const float* __restrict__ bn0g, const float* __restrict__ bn0b,
                                                 const float* __restrict__ bn0m, const float* __restrict__ bn0v,
                                                 const float* __restrict__ outW, const float* __restrict__ outb,
                                                 float* __restrict__ out) {
    __shared__ float sW[128 * 12];
    __shared__ float sSc[128], sSh[128];
    for (int i = threadIdx.x; i < 1280; i += 256) {
        int r = i / 10, c = i - r * 10;
        sW[r * 12 + c] = outW[i];
    }
    if (threadIdx.x < 128) {
        int c = threadIdx.x;
        float sc = bn0g[c] * rsqrtf(bn0v[c] + BN_EPS);
        sSc[c] = sc;
        sSh[c] = bn0b[c] - bn0m[c] * sc;
    }
    __syncthreads();
    const int wid  = blockIdx.x * 4 + (threadIdx.x >> 6);
    const int lane = threadIdx.x & 63;
    const int c0 = lane * 2;
    float2 a = *(const float2*)(x2 + (size_t)wid * 128 + c0);
    float a0 = eluf(a.x * sSc[c0] + sSh[c0]);
    float a1 = eluf(a.y * sSc[c0 + 1] + sSh[c0 + 1]);
    float p[NCLS];
    #pragma unroll
    for (int j = 0; j < NCLS; ++j)
        p[j] = a0 * sW[c0 * 12 + j] + a1 * sW[(c0 + 1) * 12 + j];
    #pragma unroll
    for (int j = 0; j < NCLS; ++j) {
        float v = p[j];
        v += __shfl_xor(v, 1);  v += __shfl_xor(v, 2);  v += __shfl_xor(v, 4);
        v += __shfl_xor(v, 8);  v += __shfl_xor(v, 16); v += __shfl_xor(v, 32);
        p[j] = v;
    }
    float z[NCLS];
    #pragma unroll
    for (int j = 0; j < NCLS; ++j) z[j] = p[j] + outb[j];
    float m = z[0];
    #pragma unroll
    for (int j = 1; j < NCLS; ++j) m = fmaxf(m, z[j]);
    float ssum = 0.f;
    #pragma unroll
    for (int j = 0; j < NCLS; ++j) ssum += __expf(z[j] - m);
    float lse = m + __logf(ssum);
    #pragma unroll
    for (int j = 0; j < NCLS; ++j)
        if (lane == j) out[(size_t)wid * NCLS + j] = z[j] - lse;
}

// ---------------- launcher ----------------
extern "C" void kernel_launch(void* const* d_in, const int* in_sizes, int n_in,
                              void* d_out, int out_size, void* d_ws, size_t ws_size,
                              hipStream_t stream) {
    const float* x        = (const float*)d_in[0];
    const int*   edge_ix  = (const int*)  d_in[1];
    const int*   scat_idx = (const int*)  d_in[2];
    const float* scat_w   = (const float*)d_in[3];
    const float* lin_W    = (const float*)d_in[4];
    const float* lin_b    = (const float*)d_in[5];
    const float* gat_W    = (const float*)d_in[6];
    const float* att_src  = (const float*)d_in[7];
    const float* att_dst  = (const float*)d_in[8];
    const float* gat_b    = (const float*)d_in[9];
    const float* mlp_W    = (const float*)d_in[10];
    const float* mlp_b    = (const float*)d_in[11];
    const float* bn_g     = (const float*)d_in[12];
    const float* bn_b     = (const float*)d_in[13];
    const float* bn_m     = (const float*)d_in[14];
    const float* bn_v     = (const float*)d_in[15];
    const float* bn0_g    = (const float*)d_in[16];
    const float* bn0_b    = (const float*)d_in[17];
    const float* bn0_m    = (const float*)d_in[18];
    const float* bn0_v    = (const float*)d_in[19];
    const float* out_W    = (const float*)d_in[20];
    const float* out_b    = (const float*)d_in[21];
    float* out = (float*)d_out;

    char* ws = (char*)d_ws;
    unsigned short* xb    = (unsigned short*)(ws + OFF_U1);
    unsigned short* xcur5 = (unsigned short*)(ws + OFF_U1);
    unsigned short* hb    = (unsigned short*)(ws + OFF_HB);
    float*          x2    = (float*)(ws + OFF_X2);
    unsigned short* agg   = (unsigned short*)(ws + OFF_AGG);
    unsigned short* gout  = (unsigned short*)(ws + OFF_GOUT);
    unsigned short* tmp4  = (unsigned short*)(ws + OFF_GOUT);
    unsigned short* wt    = (unsigned short*)(ws + OFF_WT);
    unsigned short* linWT = wt;
    unsigned short* gatWT = wt + 65536;
    unsigned short* mlpWT = wt + 65536 * 6;
    float* watt   = (float*)(ws + OFF_WATT);
    int*   off6   = (int*)(ws + OFF_OFF6);
    int2*  spp    = (int2*)(ws + OFF_SPP);
    int*   g_src  = (int*)(ws + OFF_GSRC);
    int*   cnt6   = (int*)(ws + OFF_CNT);
    int*   cur6   = cnt6 + 6 * NN;
    float* as5    = (float*)(ws + OFF_AS5);
    float* ad5    = (float*)(ws + OFF_AD5);

    const dim3 b256(256);

    // ---- CSR build (all 6 graphs), per-node cursors ----
    hipMemsetAsync(cnt6, 0, (size_t)12 * NN * 4, stream);
    count_all<<<2048, b256, 0, stream>>>(scat_idx, edge_ix, cnt6);
    exscan30k<<<6, 1024, 0, stream>>>(cnt6, off6);
    fill_all<<<2048, b256, 0, stream>>>(scat_idx, scat_w, edge_ix, off6, cur6, spp, g_src);

    // ---- dtype conversions + W@att precompute ----
    convx<<<2048, b256, 0, stream>>>(x, xb);
    transW<<<256, b256, 0, stream>>>(lin_W, linWT, 512, 128, 1);
    transW<<<640, b256, 0, stream>>>(gat_W, gatWT, 128, 512, 5);
    transW<<<640, b256, 0, stream>>>(mlp_W, mlpWT, 512, 128, 5);
    wattk<<<20, b256, 0, stream>>>(gat_W, att_src, att_dst, watt);

    // ---- h = x @ lin_W + lin_b (bf16 out) ; x2 = h (f32) ----
    mgemm<512, 128, GM_LIN><<<dim3(469, 1), b256, 0, stream>>>(
        xb, linWT, lin_b, hb, x2, nullptr, nullptr, nullptr, nullptr, NN);

    // ---- solo passes (+ fused attention scores for all 5 sets) ----
    sp_abs4<<<dim3(7500, 4), b256, 0, stream>>>(off6, spp, hb, tmp4);
    sp_fused5<<<7500, b256, 0, stream>>>(off6, spp, hb, tmp4, xcur5, watt, as5, ad5);

    // ---- 5 GAT branches: aggregate-then-multiply ----
    for (int i = 0; i < NSETS; ++i) {
        gat_agg2<<<7500, b256, 0, stream>>>(off6 + 5 * (NN + 1), g_src,
                                            as5 + (size_t)i * NN * 4, ad5 + (size_t)i * NN * 4,
                                            xcur5 + (size_t)i * NN * 128, agg);
        mgemm<128, 512, GM_GATELU><<<dim3(469, 4), b256, 0, stream>>>(
            agg, gatWT + (size_t)i * 65536, gat_b + (size_t)i * 512, gout, nullptr,
            nullptr, nullptr, nullptr, nullptr, NN);
        mgemm<512, 128, GM_MLP><<<dim3(469, 1), b256, 0, stream>>>(
            gout, mlpWT + (size_t)i * 65536, mlp_b + (size_t)i * 128, nullptr, x2,
            bn_g + (size_t)i * 128, bn_b + (size_t)i * 128,
            bn_m + (size_t)i * 128, bn_v + (size_t)i * 128, NN);
    }

    // ---- final ----
    final_out<<<7500, b256, 0, stream>>>(x2, bn0_g, bn0_b, bn0_m, bn0_v, out_W, out_b, out);
}

// Round 7
// 918.395 us; speedup vs baseline: 2.5451x; 1.0930x over previous
//
#include <hip/hip_runtime.h>
#include <cstdint>
#include <cstddef>

// ---------------- problem constants ----------------
#define NN 30000        // nodes
#define NE 400000       // edges per scatter set
#define EG (NE + NN)    // GAT edges incl self loops
#define NSETS 5
#define NCLS 10
#define BN_EPS 1e-5f
#define TOTE (NSETS * NE + EG)      // 2,430,000
#define HALFE (TOTE / 2)            // 1,215,000

typedef __bf16 bf16x8 __attribute__((ext_vector_type(8)));
typedef float  f32x4  __attribute__((ext_vector_type(4)));

// ---------------- workspace layout (bytes) ----------------
constexpr size_t alg(size_t x) { return (x + 255) & ~size_t(255); }
constexpr size_t OFF_U1    = 0;                                        // xb | xcur5
constexpr size_t OFF_HB    = OFF_U1   + alg((size_t)5 * NN * 128 * 2);
constexpr size_t OFF_X2    = OFF_HB   + alg((size_t)NN * 128 * 2);
constexpr size_t OFF_AGG   = OFF_X2   + alg((size_t)NN * 128 * 4);
constexpr size_t OFF_GOUT  = OFF_AGG  + alg((size_t)NN * 512 * 2);     // tmp4 only now
constexpr size_t OFF_WT    = OFF_GOUT + alg((size_t)NN * 512 * 2);
constexpr size_t OFF_WATT  = OFF_WT   + alg((size_t)11 * 65536 * 2);
constexpr size_t OFF_OFF6  = OFF_WATT + alg((size_t)5 * 2 * 4 * 128 * 4);
constexpr size_t OFF_SPP   = OFF_OFF6 + alg((size_t)6 * (NN + 1) * 4);
constexpr size_t OFF_GSRC  = OFF_SPP  + alg((size_t)NSETS * NE * 8);
constexpr size_t OFF_CNT   = OFF_GSRC + alg((size_t)EG * 4);
constexpr size_t OFF_AS5   = OFF_CNT  + alg((size_t)12 * NN * 4);
constexpr size_t OFF_AD5   = OFF_AS5  + alg((size_t)5 * NN * 4 * 4);
constexpr size_t WS_NEED   = OFF_AD5  + alg((size_t)5 * NN * 4 * 4);   // ~149 MB

// ---------------- helpers ----------------
__device__ __forceinline__ float lrelu02(float v) { return v > 0.f ? v : 0.2f * v; }
__device__ __forceinline__ float eluf(float v)    { return v > 0.f ? v : __expf(v) - 1.f; }
__device__ __forceinline__ float bf2f(unsigned u) {
    union { unsigned i; float f; } c; c.i = u << 16; return c.f;
}
__device__ __forceinline__ unsigned short f2bf(float f) {
    union { float f; unsigned i; } c; c.f = f;
    unsigned u = c.i + 0x7FFFu + ((c.i >> 16) & 1u);
    return (unsigned short)(u >> 16);
}
__device__ __forceinline__ void gload_lds16(const void* g, void* l) {
    __builtin_amdgcn_global_load_lds(
        (const __attribute__((address_space(1))) void*)(uintptr_t)g,
        (__attribute__((address_space(3))) void*)(unsigned)(uintptr_t)l,
        16, 0, 0);
}

// ---------------- CSR build (per-node cursors; round-5 lesson: contention rules) ----------------
__device__ __forceinline__ void count_one(int i, const int* __restrict__ scat_idx,
                                          const int* __restrict__ edge_ix, int* __restrict__ cnt6) {
    if (i < NSETS * NE) {
        int s = i / NE, e = i - s * NE;
        atomicAdd(&cnt6[s * NN + scat_idx[(size_t)s * 2 * NE + NE + e]], 1);
    } else {
        int j = i - NSETS * NE;
        int d = (j < NE) ? edge_ix[NE + j] : (j - NE);
        atomicAdd(&cnt6[5 * NN + d], 1);
    }
}

__device__ __forceinline__ void fill_one(int i, const int* __restrict__ scat_idx,
                                         const float* __restrict__ scat_w,
                                         const int* __restrict__ edge_ix,
                                         const int* __restrict__ off6, int* __restrict__ cur6,
                                         int2* __restrict__ spp, int* __restrict__ g_src) {
    if (i < NSETS * NE) {
        int s = i / NE, e = i - s * NE;
        int d = scat_idx[(size_t)s * 2 * NE + NE + e];
        int p = off6[s * (NN + 1) + d] + atomicAdd(&cur6[s * NN + d], 1);
        int2 pk;
        pk.x = scat_idx[(size_t)s * 2 * NE + e];
        pk.y = __float_as_int(scat_w[(size_t)s * NE + e]);
        spp[(size_t)s * NE + p] = pk;
    } else {
        int j = i - NSETS * NE;
        int sidx, d;
        if (j < NE) { sidx = edge_ix[j]; d = edge_ix[NE + j]; }
        else        { sidx = j - NE;     d = sidx; }
        int p = off6[5 * (NN + 1) + d] + atomicAdd(&cur6[5 * NN + d], 1);
        g_src[p] = sidx;
    }
}

__global__ void fill_all(const int* __restrict__ scat_idx, const float* __restrict__ scat_w,
                         const int* __restrict__ edge_ix, const int* __restrict__ off6,
                         int* __restrict__ cur6, int2* __restrict__ spp,
                         int* __restrict__ g_src) {
    // 2-way independent unroll: two atomic/scatter chains in flight per thread
    for (int i = blockIdx.x * blockDim.x + threadIdx.x; i < HALFE; i += gridDim.x * blockDim.x) {
        fill_one(i, scat_idx, scat_w, edge_ix, off6, cur6, spp, g_src);
        fill_one(i + HALFE, scat_idx, scat_w, edge_ix, off6, cur6, spp, g_src);
    }
}

__global__ void exscan30k(const int* __restrict__ cnt6, int* __restrict__ off6) {
    const int* cnt = cnt6 + blockIdx.x * NN;
    int* off = off6 + blockIdx.x * (NN + 1);
    constexpr int per = 30;
    __shared__ int s[1024];
    const int t = threadIdx.x;
    const int base0 = t * per;
    int sum = 0;
    #pragma unroll
    for (int i = 0; i < per; ++i) { int idx = base0 + i; sum += (idx < NN) ? cnt[idx] : 0; }
    s[t] = sum;
    __syncthreads();
    for (int d = 1; d < 1024; d <<= 1) {
        int v = (t >= d) ? s[t - d] : 0;
        __syncthreads();
        s[t] += v;
        __syncthreads();
    }
    int run = s[t] - sum;
    #pragma unroll
    for (int i = 0; i < per; ++i) {
        int idx = base0 + i;
        if (idx < NN) { off[idx] = run; run += cnt[idx]; }
    }
    if (t == 1023) off[NN] = s[1023];
}

// ---------------- prep1: count_all | convx | transW x3 | wattk (independent, one launch) ----------------
#define PREP_CNT_B 2048
#define PREP_CVX_B 1024
#define PREP_TRW_B 512
#define PREP_WAT_B 20
#define PREP_GRID (PREP_CNT_B + PREP_CVX_B + PREP_TRW_B + PREP_WAT_B)

__global__ void prep1(const int* __restrict__ scat_idx, const int* __restrict__ edge_ix,
                      int* __restrict__ cnt6,
                      const float* __restrict__ x, unsigned short* __restrict__ xb,
                      const float* __restrict__ lin_W, const float* __restrict__ gat_W,
                      const float* __restrict__ mlp_W,
                      unsigned short* __restrict__ linWT, unsigned short* __restrict__ gatWT,
                      unsigned short* __restrict__ mlpWT,
                      const float* __restrict__ att_src, const float* __restrict__ att_dst,
                      float* __restrict__ watt) {
    const int b = blockIdx.x;
    if (b < PREP_CNT_B) {
        for (int i = b * 256 + threadIdx.x; i < HALFE; i += PREP_CNT_B * 256) {
            count_one(i, scat_idx, edge_ix, cnt6);
            count_one(i + HALFE, scat_idx, edge_ix, cnt6);
        }
    } else if (b < PREP_CNT_B + PREP_CVX_B) {
        const int bb = b - PREP_CNT_B;
        const int total = NN * 512 / 4;
        for (int i = bb * 256 + threadIdx.x; i < total; i += PREP_CVX_B * 256) {
            float4 v = *(const float4*)(x + (size_t)i * 4);
            ushort4 o;
            o.x = f2bf(v.x); o.y = f2bf(v.y); o.z = f2bf(v.z); o.w = f2bf(v.w);
            *(ushort4*)(xb + (size_t)i * 4) = o;
        }
    } else if (b < PREP_CNT_B + PREP_CVX_B + PREP_TRW_B) {
        const int bb = b - PREP_CNT_B - PREP_CVX_B;
        const int total = 65536 + 2 * 327680;
        for (int i = bb * 256 + threadIdx.x; i < total; i += PREP_TRW_B * 256) {
            if (i < 65536) {                       // linWT [128][512] <- lin_W [512][128]
                int n = i >> 9, k = i & 511;
                linWT[i] = f2bf(lin_W[(size_t)k * 128 + n]);
            } else if (i < 65536 + 327680) {       // gatWT [5][512][128] <- gat_W [5][128][512]
                int li = i - 65536;
                int st = li >> 16, r = li & 65535;
                int n = r >> 7, k = r & 127;
                gatWT[li] = f2bf(gat_W[(size_t)st * 65536 + (size_t)k * 512 + n]);
            } else {                               // mlpWT [5][128][512] <- mlp_W [5][512][128]
                int li = i - 65536 - 327680;
                int st = li >> 16, r = li & 65535;
                int n = r >> 9, k = r & 511;
                mlpWT[li] = f2bf(mlp_W[(size_t)st * 65536 + (size_t)k * 128 + n]);
            }
        }
    } else {
        const int tid = (b - PREP_CNT_B - PREP_CVX_B - PREP_TRW_B) * 256 + threadIdx.x;
        if (tid < 5120) {
            int k = tid & 127, h = (tid >> 7) & 3, tt = (tid >> 9) & 1, i = tid >> 10;
            const float* att = (tt == 0 ? att_src : att_dst) + ((size_t)i * 4 + h) * 128;
            const float* Wr  = gat_W + ((size_t)i * 128 + k) * 512 + h * 128;
            float s = 0.f;
            #pragma unroll 8
            for (int c = 0; c < 128; ++c) s = fmaf(Wr[c], att[c], s);
            watt[tid] = s;
        }
    }
}

// ---------------- staging helper: 64-k slab of ROWS rows, XOR-swizzled chunks ----------------
template<int ROWS>
__device__ __forceinline__ void stage64(const unsigned short* __restrict__ src, int ld,
                                        int row0, int maxrow, int k0, char* lds, int t) {
    const int wave = t >> 6, lane = t & 63;
    const int sub = lane >> 3;
    const int kch = (lane & 7) ^ sub;
    for (int j = wave; j < ROWS / 8; j += 4) {
        int grow = row0 + j * 8 + sub;
        if (grow > maxrow) grow = maxrow;
        gload_lds16(src + (size_t)grow * ld + k0 + kch * 8, lds + j * 1024);
    }
}

// ---------------- MFMA bf16 GEMM (LIN): hb=bf16(A@B+bias), x2=f32(same) ----------------
__global__ void __launch_bounds__(256) mgemm_lin(const unsigned short* __restrict__ A,
                                                 const unsigned short* __restrict__ BT,
                                                 const float* __restrict__ bias,
                                                 unsigned short* __restrict__ outb,
                                                 float* __restrict__ x2) {
    constexpr int K = 512, NC = 128;
    __shared__ __align__(16) char As[64 * 128];
    __shared__ __align__(16) char Bs[128 * 128];
    const int t = threadIdx.x, wave = t >> 6, lane = t & 63;
    const int bm = blockIdx.x * 64, bn = 0;
    const int wr = (wave >> 1) * 32, wc = (wave & 1) * 64;
    const int l15 = lane & 15, l4 = lane >> 4;
    const int rsw = (l15 & 7) << 4;
    f32x4 acc[2][4] = {};

    for (int kt = 0; kt < K; kt += 64) {
        stage64<64>(A, K, bm, NN - 1, kt, As, t);
        stage64<128>(BT, K, bn, NC - 1, kt, Bs, t);
        __syncthreads();
        #pragma unroll
        for (int kk = 0; kk < 2; ++kk) {
            bf16x8 af[2], bf[4];
            const int koff = kk * 64 + l4 * 16;
            #pragma unroll
            for (int fm = 0; fm < 2; ++fm)
                af[fm] = *(const bf16x8*)(As + (wr + fm * 16 + l15) * 128 + (koff ^ rsw));
            #pragma unroll
            for (int fn = 0; fn < 4; ++fn)
                bf[fn] = *(const bf16x8*)(Bs + (wc + fn * 16 + l15) * 128 + (koff ^ rsw));
            #pragma unroll
            for (int fm = 0; fm < 2; ++fm)
                #pragma unroll
                for (int fn = 0; fn < 4; ++fn)
                    acc[fm][fn] = __builtin_amdgcn_mfma_f32_16x16x32_bf16(af[fm], bf[fn], acc[fm][fn], 0, 0, 0);
        }
        __syncthreads();
    }

    #pragma unroll
    for (int fn = 0; fn < 4; ++fn) {
        const int c = wc + fn * 16 + l15;
        const float bias_c = bias[c];
        #pragma unroll
        for (int fm = 0; fm < 2; ++fm) {
            #pragma unroll
            for (int rg = 0; rg < 4; ++rg) {
                int r = bm + wr + fm * 16 + l4 * 4 + rg;
                if (r < NN) {
                    float v = acc[fm][fn][rg] + bias_c;
                    outb[(size_t)r * NC + c] = f2bf(v);
                    x2[(size_t)r * NC + c] = v;
                }
            }
        }
    }
}

// ---------------- fused GATELU + MLP + BN-accumulate ----------------
// Per 64-row block: for each head h: gout_h = elu(agg[:,h*128:+128] @ gat_W_h + gat_b_h)
// (kept in swizzled LDS tile), acc2 += gout_h @ mlp_W[h*128:+128, :]. Epilogue: x2 += BN(acc2+mlp_b).
__global__ void __launch_bounds__(256) fusedGM(const unsigned short* __restrict__ agg,
                                               const unsigned short* __restrict__ gatWT,  // [512][128]
                                               const unsigned short* __restrict__ mlpWT,  // [128][512]
                                               const float* __restrict__ gat_b,
                                               const float* __restrict__ mlp_b,
                                               const float* __restrict__ bng, const float* __restrict__ bnb,
                                               const float* __restrict__ bnm, const float* __restrict__ bnv,
                                               float* __restrict__ x2) {
    __shared__ __align__(16) char U[49152];       // A_lo|A_hi|B_lo|B_hi  or  Bs2a|Bs2b
    __shared__ __align__(16) char gtile[16384];   // [64][128] bf16, chunk-swizzled
    const int t = threadIdx.x, wave = t >> 6, lane = t & 63;
    const int bm = blockIdx.x * 64;
    const int wr = (wave >> 1) * 32, wc = (wave & 1) * 64;
    const int l15 = lane & 15, l4 = lane >> 4;
    const int rsw = (l15 & 7) << 4;
    f32x4 acc2[2][4] = {};

    #pragma unroll
    for (int h = 0; h < 4; ++h) {
        // ---- phase A: stage agg 64x128 slab (2x64k) + gatWT head block 128x128 ----
        stage64<64>(agg, 512, bm, NN - 1, h * 128,       U,         t);
        stage64<64>(agg, 512, bm, NN - 1, h * 128 + 64,  U + 8192,  t);
        stage64<128>(gatWT, 128, h * 128, 511, 0,        U + 16384, t);
        stage64<128>(gatWT, 128, h * 128, 511, 64,       U + 32768, t);
        __syncthreads();

        f32x4 a1[2][4] = {};
        #pragma unroll
        for (int ks = 0; ks < 4; ++ks) {
            const char* Asb = U + (ks >> 1) * 8192;
            const char* Bsb = U + 16384 + (ks >> 1) * 16384;
            const int koff = (ks & 1) * 64 + l4 * 16;
            bf16x8 af[2], bf[4];
            #pragma unroll
            for (int fm = 0; fm < 2; ++fm)
                af[fm] = *(const bf16x8*)(Asb + (wr + fm * 16 + l15) * 128 + (koff ^ rsw));
            #pragma unroll
            for (int fn = 0; fn < 4; ++fn)
                bf[fn] = *(const bf16x8*)(Bsb + (wc + fn * 16 + l15) * 128 + (koff ^ rsw));
            #pragma unroll
            for (int fm = 0; fm < 2; ++fm)
                #pragma unroll
                for (int fn = 0; fn < 4; ++fn)
                    a1[fm][fn] = __builtin_amdgcn_mfma_f32_16x16x32_bf16(af[fm], bf[fn], a1[fm][fn], 0, 0, 0);
        }
        __syncthreads();   // all reads of U done before Bs2 overwrite

        // ---- ELU + bias -> gtile (bf16, chunk ^ (row&7) swizzle) ; stage mlpWT head slabs ----
        #pragma unroll
        for (int fn = 0; fn < 4; ++fn) {
            const int cc = wc + fn * 16 + l15;
            const float gb = gat_b[h * 128 + cc];
            #pragma unroll
            for (int fm = 0; fm < 2; ++fm) {
                #pragma unroll
                for (int rg = 0; rg < 4; ++rg) {
                    const int r = wr + fm * 16 + l4 * 4 + rg;
                    const unsigned short v = f2bf(eluf(a1[fm][fn][rg] + gb));
                    *(unsigned short*)(gtile + r * 256 + ((((cc >> 3) ^ (r & 7)) << 4) | ((cc & 7) << 1))) = v;
                }
            }
        }
        stage64<128>(mlpWT, 512, 0, 127, h * 128,      U,         t);
        stage64<128>(mlpWT, 512, 0, 127, h * 128 + 64, U + 16384, t);
        __syncthreads();

        // ---- phase B: acc2 += gtile @ mlpWT_head ----
        #pragma unroll
        for (int ks = 0; ks < 4; ++ks) {
            const int s2 = ks >> 1, kk = ks & 1;
            const char* slab = U + s2 * 16384;
            bf16x8 af[2], bf[4];
            #pragma unroll
            for (int fm = 0; fm < 2; ++fm) {
                const int r2 = wr + fm * 16 + l15;
                const int chunk = (s2 * 8 + kk * 4 + l4) ^ (r2 & 7);
                af[fm] = *(const bf16x8*)(gtile + r2 * 256 + (chunk << 4));
            }
            const int koff = kk * 64 + l4 * 16;
            #pragma unroll
            for (int fn = 0; fn < 4; ++fn)
                bf[fn] = *(const bf16x8*)(slab + (wc + fn * 16 + l15) * 128 + (koff ^ rsw));
            #pragma unroll
            for (int fm = 0; fm < 2; ++fm)
                #pragma unroll
                for (int fn = 0; fn < 4; ++fn)
                    acc2[fm][fn] = __builtin_amdgcn_mfma_f32_16x16x32_bf16(af[fm], bf[fn], acc2[fm][fn], 0, 0, 0);
        }
        __syncthreads();   // before next head overwrites U & gtile
    }

    // ---- epilogue: x2 += BN(acc2 + mlp_b) ----
    #pragma unroll
    for (int fn = 0; fn < 4; ++fn) {
        const int c = wc + fn * 16 + l15;
        const float sc = bng[c] * rsqrtf(bnv[c] + BN_EPS);
        const float sh = bnb[c] - bnm[c] * sc;
        const float mb = mlp_b[c];
        #pragma unroll
        for (int fm = 0; fm < 2; ++fm) {
            #pragma unroll
            for (int rg = 0; rg < 4; ++rg) {
                int r = bm + wr + fm * 16 + l4 * 4 + rg;
                if (r < NN)
                    x2[(size_t)r * 128 + c] += (acc2[fm][fn][rg] + mb) * sc + sh;
            }
        }
    }
}

// ---------------- phase 0: tmp_y = abs(sp(y+1, hb)), 4-way edge unroll ----------------
__global__ void __launch_bounds__(256) sp_abs4(const int* __restrict__ off6,
                                               const int2* __restrict__ spp,
                                               const unsigned short* __restrict__ hb,
                                               unsigned short* __restrict__ tmp4) {
    const int y = blockIdx.y;
    const int* off = off6 + (y + 1) * (NN + 1);
    const int2* pk = spp + (size_t)(y + 1) * NE;
    unsigned short* out = tmp4 + (size_t)y * NN * 128;

    const int wid  = blockIdx.x * 4 + (threadIdx.x >> 6);
    const int lane = threadIdx.x & 63;
    const int co   = lane * 2;
    const int s0 = off[wid], s1 = off[wid + 1];
    float a0 = 0.f, a1 = 0.f;
    int j = s0;
    for (; j + 3 < s1; j += 4) {
        int2 e0 = pk[j], e1 = pk[j + 1], e2 = pk[j + 2], e3 = pk[j + 3];
        unsigned v0 = *(const unsigned*)(hb + (size_t)e0.x * 128 + co);
        unsigned v1 = *(const unsigned*)(hb + (size_t)e1.x * 128 + co);
        unsigned v2 = *(const unsigned*)(hb + (size_t)e2.x * 128 + co);
        unsigned v3 = *(const unsigned*)(hb + (size_t)e3.x * 128 + co);
        float w0 = __int_as_float(e0.y), w1 = __int_as_float(e1.y);
        float w2 = __int_as_float(e2.y), w3 = __int_as_float(e3.y);
        a0 = fmaf(w0, bf2f(v0 & 0xffffu), a0); a1 = fmaf(w0, bf2f(v0 >> 16), a1);
        a0 = fmaf(w1, bf2f(v1 & 0xffffu), a0); a1 = fmaf(w1, bf2f(v1 >> 16), a1);
        a0 = fmaf(w2, bf2f(v2 & 0xffffu), a0); a1 = fmaf(w2, bf2f(v2 >> 16), a1);
        a0 = fmaf(w3, bf2f(v3 & 0xffffu), a0); a1 = fmaf(w3, bf2f(v3 >> 16), a1);
    }
    for (; j < s1; ++j) {
        int2 e = pk[j];
        float wj = __int_as_float(e.y);
        unsigned v = *(const unsigned*)(hb + (size_t)e.x * 128 + co);
        a0 = fmaf(wj, bf2f(v & 0xffffu), a0);
        a1 = fmaf(wj, bf2f(v >> 16), a1);
    }
    a0 = fabsf(a0); a1 = fabsf(a1);
    unsigned o = (unsigned)f2bf(a0) | ((unsigned)f2bf(a1) << 16);
    *(unsigned*)(out + (size_t)wid * 128 + co) = o;
}

// ---------------- phase 1: xcur_y = sp(0, {hb,tmp0..3}) fused + attention scores ----------------
__global__ void __launch_bounds__(256) sp_fused5(const int* __restrict__ off0,
                                                 const int2* __restrict__ spp0,
                                                 const unsigned short* __restrict__ hb,
                                                 const unsigned short* __restrict__ tmp4,
                                                 unsigned short* __restrict__ xcur5,
                                                 const float* __restrict__ watt,
                                                 float* __restrict__ as5,
                                                 float* __restrict__ ad5) {
    __shared__ float sWatt[5120];           // [5][2][4][128]
    for (int i = threadIdx.x; i < 5120; i += 256) sWatt[i] = watt[i];
    __syncthreads();

    const int wid  = blockIdx.x * 4 + (threadIdx.x >> 6);
    const int lane = threadIdx.x & 63;
    const int co   = lane * 2;
    const int s0 = off0[wid], s1 = off0[wid + 1];
    const unsigned short* t0 = tmp4;
    const unsigned short* t1 = tmp4 + (size_t)1 * NN * 128;
    const unsigned short* t2 = tmp4 + (size_t)2 * NN * 128;
    const unsigned short* t3 = tmp4 + (size_t)3 * NN * 128;

    float a[5][2] = {};
    int j = s0;
    for (; j + 1 < s1; j += 2) {
        int2 eA = spp0[j], eB = spp0[j + 1];
        size_t rA = (size_t)eA.x * 128 + co, rB = (size_t)eB.x * 128 + co;
        unsigned vA0 = *(const unsigned*)(hb + rA), vB0 = *(const unsigned*)(hb + rB);
        unsigned vA1 = *(const unsigned*)(t0 + rA), vB1 = *(const unsigned*)(t0 + rB);
        unsigned vA2 = *(const unsigned*)(t1 + rA), vB2 = *(const unsigned*)(t1 + rB);
        unsigned vA3 = *(const unsigned*)(t2 + rA), vB3 = *(const unsigned*)(t2 + rB);
        unsigned vA4 = *(const unsigned*)(t3 + rA), vB4 = *(const unsigned*)(t3 + rB);
        float wA = __int_as_float(eA.y), wB = __int_as_float(eB.y);
        a[0][0] = fmaf(wA, bf2f(vA0 & 0xffffu), a[0][0]); a[0][1] = fmaf(wA, bf2f(vA0 >> 16), a[0][1]);
        a[1][0] = fmaf(wA, bf2f(vA1 & 0xffffu), a[1][0]); a[1][1] = fmaf(wA, bf2f(vA1 >> 16), a[1][1]);
        a[2][0] = fmaf(wA, bf2f(vA2 & 0xffffu), a[2][0]); a[2][1] = fmaf(wA, bf2f(vA2 >> 16), a[2][1]);
        a[3][0] = fmaf(wA, bf2f(vA3 & 0xffffu), a[3][0]); a[3][1] = fmaf(wA, bf2f(vA3 >> 16), a[3][1]);
        a[4][0] = fmaf(wA, bf2f(vA4 & 0xffffu), a[4][0]); a[4][1] = fmaf(wA, bf2f(vA4 >> 16), a[4][1]);
        a[0][0] = fmaf(wB, bf2f(vB0 & 0xffffu), a[0][0]); a[0][1] = fmaf(wB, bf2f(vB0 >> 16), a[0][1]);
        a[1][0] = fmaf(wB, bf2f(vB1 & 0xffffu), a[1][0]); a[1][1] = fmaf(wB, bf2f(vB1 >> 16), a[1][1]);
        a[2][0] = fmaf(wB, bf2f(vB2 & 0xffffu), a[2][0]); a[2][1] = fmaf(wB, bf2f(vB2 >> 16), a[2][1]);
        a[3][0] = fmaf(wB, bf2f(vB3 & 0xffffu), a[3][0]); a[3][1] = fmaf(wB, bf2f(vB3 >> 16), a[3][1]);
        a[4][0] = fmaf(wB, bf2f(vB4 & 0xffffu), a[4][0]); a[4][1] = fmaf(wB, bf2f(vB4 >> 16), a[4][1]);
    }
    if (j < s1) {
        int2 e = spp0[j];
        size_t r = (size_t)e.x * 128 + co;
        unsigned v0 = *(const unsigned*)(hb + r);
        unsigned v1 = *(const unsigned*)(t0 + r);
        unsigned v2 = *(const unsigned*)(t1 + r);
        unsigned v3 = *(const unsigned*)(t2 + r);
        unsigned v4 = *(const unsigned*)(t3 + r);
        float wj = __int_as_float(e.y);
        a[0][0] = fmaf(wj, bf2f(v0 & 0xffffu), a[0][0]); a[0][1] = fmaf(wj, bf2f(v0 >> 16), a[0][1]);
        a[1][0] = fmaf(wj, bf2f(v1 & 0xffffu), a[1][0]); a[1][1] = fmaf(wj, bf2f(v1 >> 16), a[1][1]);
        a[2][0] = fmaf(wj, bf2f(v2 & 0xffffu), a[2][0]); a[2][1] = fmaf(wj, bf2f(v2 >> 16), a[2][1]);
        a[3][0] = fmaf(wj, bf2f(v3 & 0xffffu), a[3][0]); a[3][1] = fmaf(wj, bf2f(v3 >> 16), a[3][1]);
        a[4][0] = fmaf(wj, bf2f(v4 & 0xffffu), a[4][0]); a[4][1] = fmaf(wj, bf2f(v4 >> 16), a[4][1]);
    }
    #pragma unroll
    for (int y = 0; y < 5; ++y) {
        unsigned o = (unsigned)f2bf(a[y][0]) | ((unsigned)f2bf(a[y][1]) << 16);
        *(unsigned*)(xcur5 + (size_t)y * NN * 128 + (size_t)wid * 128 + co) = o;
    }

    #pragma unroll
    for (int i = 0; i < 5; ++i) {
        #pragma unroll
        for (int h = 0; h < 4; ++h) {
            const float* wS = sWatt + ((i * 2 + 0) * 4 + h) * 128;
            const float* wD = sWatt + ((i * 2 + 1) * 4 + h) * 128;
            float ps = a[i][0] * wS[co] + a[i][1] * wS[co + 1];
            float pd = a[i][0] * wD[co] + a[i][1] * wD[co + 1];
            #pragma unroll
            for (int dd = 1; dd < 64; dd <<= 1) { ps += __shfl_xor(ps, dd); pd += __shfl_xor(pd, dd); }
            if (lane == 0) {
                as5[(size_t)i * NN * 4 + (size_t)wid * 4 + h] = ps;
                ad5[(size_t)i * NN * 4 + (size_t)wid * 4 + h] = pd;
            }
        }
    }
}

// ---------------- GAT aggregation on xcur (pre-W) ----------------
__device__ __forceinline__ void acc8(float* a, float al, uint4 v) {
    a[0] = fmaf(al, bf2f(v.x & 0xffffu), a[0]); a[1] = fmaf(al, bf2f(v.x >> 16), a[1]);
    a[2] = fmaf(al, bf2f(v.y & 0xffffu), a[2]); a[3] = fmaf(al, bf2f(v.y >> 16), a[3]);
    a[4] = fmaf(al, bf2f(v.z & 0xffffu), a[4]); a[5] = fmaf(al, bf2f(v.z >> 16), a[5]);
    a[6] = fmaf(al, bf2f(v.w & 0xffffu), a[6]); a[7] = fmaf(al, bf2f(v.w >> 16), a[7]);
}

__global__ void __launch_bounds__(256) gat_agg2(const int* __restrict__ goff, const int* __restrict__ gsrc,
                                                const float* __restrict__ as_, const float* __restrict__ ad_,
                                                const unsigned short* __restrict__ xcur,
                                                unsigned short* __restrict__ agg) {
    const int wid  = blockIdx.x * 4 + (threadIdx.x >> 6);
    const int lane = threadIdx.x & 63;
    const int hd   = lane >> 4;
    const int cl   = (lane & 15) * 8;
    const int s0 = goff[wid], s1 = goff[wid + 1];
    const float4 adv4 = *(const float4*)(ad_ + (size_t)wid * 4);

    float m[4] = {-1e30f, -1e30f, -1e30f, -1e30f};
    float s[4] = {0.f, 0.f, 0.f, 0.f};
    for (int j = s0 + lane; j < s1; j += 64) {
        const int si = gsrc[j];
        float4 av = *(const float4*)(as_ + (size_t)si * 4);
        float e[4] = {lrelu02(av.x + adv4.x), lrelu02(av.y + adv4.y),
                      lrelu02(av.z + adv4.z), lrelu02(av.w + adv4.w)};
        #pragma unroll
        for (int h = 0; h < 4; ++h) {
            if (e[h] > m[h]) { s[h] = s[h] * __expf(m[h] - e[h]) + 1.f; m[h] = e[h]; }
            else             { s[h] += __expf(e[h] - m[h]); }
        }
    }
    #pragma unroll
    for (int d = 1; d < 64; d <<= 1) {
        #pragma unroll
        for (int h = 0; h < 4; ++h) {
            float om = __shfl_xor(m[h], d);
            float os = __shfl_xor(s[h], d);
            float nm = fmaxf(m[h], om);
            s[h] = s[h] * __expf(m[h] - nm) + os * __expf(om - nm);
            m[h] = nm;
        }
    }
    const float advh = hd == 0 ? adv4.x : hd == 1 ? adv4.y : hd == 2 ? adv4.z : adv4.w;
    const float mv   = hd == 0 ? m[0]   : hd == 1 ? m[1]   : hd == 2 ? m[2]   : m[3];
    const float dv   = hd == 0 ? s[0]   : hd == 1 ? s[1]   : hd == 2 ? s[2]   : s[3];
    const float inv  = 1.f / (dv + 1e-16f);

    float ac[8] = {};
    int j = s0;
    for (; j + 1 < s1; j += 2) {
        int i0 = gsrc[j], i1 = gsrc[j + 1];
        float q0 = as_[(size_t)i0 * 4 + hd], q1 = as_[(size_t)i1 * 4 + hd];
        uint4 v0 = *(const uint4*)(xcur + (size_t)i0 * 128 + cl);
        uint4 v1 = *(const uint4*)(xcur + (size_t)i1 * 128 + cl);
        float al0 = __expf(lrelu02(q0 + advh) - mv) * inv;
        float al1 = __expf(lrelu02(q1 + advh) - mv) * inv;
        acc8(ac, al0, v0); acc8(ac, al1, v1);
    }
    if (j < s1) {
        int si = gsrc[j];
        float q = as_[(size_t)si * 4 + hd];
        uint4 v = *(const uint4*)(xcur + (size_t)si * 128 + cl);
        float al = __expf(lrelu02(q + advh) - mv) * inv;
        acc8(ac, al, v);
    }
    uint4 ov;
    ov.x = (unsigned)f2bf(ac[0]) | ((unsigned)f2bf(ac[1]) << 16);
    ov.y = (unsigned)f2bf(ac[2]) | ((unsigned)f2bf(ac[3]) << 16);
    ov.z = (unsigned)f2bf(ac[4]) | ((unsigned)f2bf(ac[5]) << 16);
    ov.w = (unsigned)f2bf(ac[6]) | ((unsigned)f2bf(ac[7]) << 16);
    *(uint4*)(agg + (size_t)wid * 512 + hd * 128 + cl) = ov;
}

// ---------------- final: out = log_softmax( elu(bn0(x2)) @ outW + outb ) ----------------
__global__ void __launch_bounds__(256) final_out(const float* __restrict__ x2,
                                                 const float* __restrict__ bn0g, const float* __restrict__ bn0b,
                                                 const float* __restrict__ bn0m, const float* __restrict__ bn0v,
                                                 const float* __restrict__ outW, const float* __restrict__ outb,
                                                 float* __restrict__ out) {
    __shared__ float sW[128 * 12];
    __shared__ float sSc[128], sSh[128];
    for (int i = threadIdx.x; i < 1280; i += 256) {
        int r = i / 10, c = i - r * 10;
        sW[r * 12 + c] = outW[i];
    }
    if (threadIdx.x < 128) {
        int c = threadIdx.x;
        float sc = bn0g[c] * rsqrtf(bn0v[c] + BN_EPS);
        sSc[c] = sc;
        sSh[c] = bn0b[c] - bn0m[c] * sc;
    }
    __syncthreads();
    const int wid  = blockIdx.x * 4 + (threadIdx.x >> 6);
    const int lane = threadIdx.x & 63;
    const int c0 = lane * 2;
    float2 a = *(const float2*)(x2 + (size_t)wid * 128 + c0);
    float a0 = eluf(a.x * sSc[c0] + sSh[c0]);
    float a1 = eluf(a.y * sSc[c0 + 1] + sSh[c0 + 1]);
    float p[NCLS];
    #pragma unroll
    for (int j = 0; j < NCLS; ++j)
        p[j] = a0 * sW[c0 * 12 + j] + a1 * sW[(c0 + 1) * 12 + j];
    #pragma unroll
    for (int j = 0; j < NCLS; ++j) {
        float v = p[j];
        v += __shfl_xor(v, 1);  v += __shfl_xor(v, 2);  v += __shfl_xor(v, 4);
        v += __shfl_xor(v, 8);  v += __shfl_xor(v, 16); v += __shfl_xor(v, 32);
        p[j] = v;
    }
    float z[NCLS];
    #pragma unroll
    for (int j = 0; j < NCLS; ++j) z[j] = p[j] + outb[j];
    float m = z[0];
    #pragma unroll
    for (int j = 1; j < NCLS; ++j) m = fmaxf(m, z[j]);
    float ssum = 0.f;
    #pragma unroll
    for (int j = 0; j < NCLS; ++j) ssum += __expf(z[j] - m);
    float lse = m + __logf(ssum);
    #pragma unroll
    for (int j = 0; j < NCLS; ++j)
        if (lane == j) out[(size_t)wid * NCLS + j] = z[j] - lse;
}

// ---------------- launcher ----------------
extern "C" void kernel_launch(void* const* d_in, const int* in_sizes, int n_in,
                              void* d_out, int out_size, void* d_ws, size_t ws_size,
                              hipStream_t stream) {
    const float* x        = (const float*)d_in[0];
    const int*   edge_ix  = (const int*)  d_in[1];
    const int*   scat_idx = (const int*)  d_in[2];
    const float* scat_w   = (const float*)d_in[3];
    const float* lin_W    = (const float*)d_in[4];
    const float* lin_b    = (const float*)d_in[5];
    const float* gat_W    = (const float*)d_in[6];
    const float* att_src  = (const float*)d_in[7];
    const float* att_dst  = (const float*)d_in[8];
    const float* gat_b    = (const float*)d_in[9];
    const float* mlp_W    = (const float*)d_in[10];
    const float* mlp_b    = (const float*)d_in[11];
    const float* bn_g     = (const float*)d_in[12];
    const float* bn_b     = (const float*)d_in[13];
    const float* bn_m     = (const float*)d_in[14];
    const float* bn_v     = (const float*)d_in[15];
    const float* bn0_g    = (const float*)d_in[16];
    const float* bn0_b    = (const float*)d_in[17];
    const float* bn0_m    = (const float*)d_in[18];
    const float* bn0_v    = (const float*)d_in[19];
    const float* out_W    = (const float*)d_in[20];
    const float* out_b    = (const float*)d_in[21];
    float* out = (float*)d_out;

    char* ws = (char*)d_ws;
    unsigned short* xb    = (unsigned short*)(ws + OFF_U1);
    unsigned short* xcur5 = (unsigned short*)(ws + OFF_U1);
    unsigned short* hb    = (unsigned short*)(ws + OFF_HB);
    float*          x2    = (float*)(ws + OFF_X2);
    unsigned short* agg   = (unsigned short*)(ws + OFF_AGG);
    unsigned short* tmp4  = (unsigned short*)(ws + OFF_GOUT);
    unsigned short* wt    = (unsigned short*)(ws + OFF_WT);
    unsigned short* linWT = wt;
    unsigned short* gatWT = wt + 65536;
    unsigned short* mlpWT = wt + 65536 * 6;
    float* watt   = (float*)(ws + OFF_WATT);
    int*   off6   = (int*)(ws + OFF_OFF6);
    int2*  spp    = (int2*)(ws + OFF_SPP);
    int*   g_src  = (int*)(ws + OFF_GSRC);
    int*   cnt6   = (int*)(ws + OFF_CNT);
    int*   cur6   = cnt6 + 6 * NN;
    float* as5    = (float*)(ws + OFF_AS5);
    float* ad5    = (float*)(ws + OFF_AD5);

    const dim3 b256(256);

    // ---- CSR count (+ conversions, transposes, watt) in one launch ----
    hipMemsetAsync(cnt6, 0, (size_t)12 * NN * 4, stream);
    prep1<<<PREP_GRID, b256, 0, stream>>>(scat_idx, edge_ix, cnt6, x, xb,
                                          lin_W, gat_W, mlp_W, linWT, gatWT, mlpWT,
                                          att_src, att_dst, watt);
    exscan30k<<<6, 1024, 0, stream>>>(cnt6, off6);
    fill_all<<<2048, b256, 0, stream>>>(scat_idx, scat_w, edge_ix, off6, cur6, spp, g_src);

    // ---- h = x @ lin_W + lin_b (bf16 out) ; x2 = h (f32) ----
    mgemm_lin<<<469, b256, 0, stream>>>(xb, linWT, lin_b, hb, x2);

    // ---- solo passes (+ fused attention scores for all 5 sets) ----
    sp_abs4<<<dim3(7500, 4), b256, 0, stream>>>(off6, spp, hb, tmp4);
    sp_fused5<<<7500, b256, 0, stream>>>(off6, spp, hb, tmp4, xcur5, watt, as5, ad5);

    // ---- 5 GAT branches: aggregate -> fused (gatW+ELU) @ mlpW + BN accumulate ----
    for (int i = 0; i < NSETS; ++i) {
        gat_agg2<<<7500, b256, 0, stream>>>(off6 + 5 * (NN + 1), g_src,
                                            as5 + (size_t)i * NN * 4, ad5 + (size_t)i * NN * 4,
                                            xcur5 + (size_t)i * NN * 128, agg);
        fusedGM<<<469, b256, 0, stream>>>(agg, gatWT + (size_t)i * 65536, mlpWT + (size_t)i * 65536,
                                          gat_b + (size_t)i * 512, mlp_b + (size_t)i * 128,
                                          bn_g + (size_t)i * 128, bn_b + (size_t)i * 128,
                                          bn_m + (size_t)i * 128, bn_v + (size_t)i * 128, x2);
    }

    // ---- final ----
    final_out<<<7500, b256, 0, stream>>>(x2, bn0_g, bn0_b, bn0_m, bn0_v, out_W, out_b, out);
}

// Round 8
// 821.095 us; speedup vs baseline: 2.8467x; 1.1185x over previous
//
#include <hip/hip_runtime.h>
#include <cstdint>
#include <cstddef>

// ---------------- problem constants ----------------
#define NN 30000        // nodes
#define NE 400000       // edges per scatter set
#define EG (NE + NN)    // GAT edges incl self loops
#define NSETS 5
#define NCLS 10
#define BN_EPS 1e-5f
#define TOTE (NSETS * NE + EG)      // 2,430,000
#define HALFE (TOTE / 2)

// bucketed CSR build
#define NBKT 118        // buckets of 256 dst nodes (30000/256 -> 118)
#define CHUNK 4096
#define NWG_SET 98      // ceil(400000/4096)
#define NWG_GAT 105     // ceil(430000/4096)
#define NWGMAX 105
#define NBLK_BIN (5 * NWG_SET + NWG_GAT)   // 595
#define NBLK_SORT (6 * NBKT)               // 708

typedef __bf16 bf16x8 __attribute__((ext_vector_type(8)));
typedef float  f32x4  __attribute__((ext_vector_type(4)));

// ---------------- workspace layout (bytes) ----------------
constexpr size_t alg(size_t x) { return (x + 255) & ~size_t(255); }
constexpr size_t OFF_U1    = 0;                                        // xb | xcur5
constexpr size_t OFF_HB    = OFF_U1   + alg((size_t)5 * NN * 128 * 2);
constexpr size_t OFF_X2    = OFF_HB   + alg((size_t)NN * 128 * 2);
constexpr size_t OFF_AGG   = OFF_X2   + alg((size_t)NN * 128 * 4);
constexpr size_t OFF_GOUT  = OFF_AGG  + alg((size_t)NN * 512 * 2);     // CSR staging -> tmp4
constexpr size_t OFF_WT    = OFF_GOUT + alg((size_t)NN * 512 * 2);
constexpr size_t OFF_WATT  = OFF_WT   + alg((size_t)11 * 65536 * 2);
constexpr size_t OFF_OFF6  = OFF_WATT + alg((size_t)5 * 2 * 4 * 128 * 4);
constexpr size_t OFF_SPP   = OFF_OFF6 + alg((size_t)6 * (NN + 1) * 4);
constexpr size_t OFF_GSRC  = OFF_SPP  + alg((size_t)NSETS * NE * 8);
constexpr size_t OFF_CNT   = OFF_GSRC + alg((size_t)EG * 4);
constexpr size_t OFF_AS5   = OFF_CNT  + alg((size_t)12 * NN * 4);
constexpr size_t OFF_AD5   = OFF_AS5  + alg((size_t)5 * NN * 4 * 4);
constexpr size_t WS_NEED   = OFF_AD5  + alg((size_t)5 * NN * 4 * 4);   // ~149 MB

// ---------------- helpers ----------------
__device__ __forceinline__ float lrelu02(float v) { return v > 0.f ? v : 0.2f * v; }
__device__ __forceinline__ float eluf(float v)    { return v > 0.f ? v : __expf(v) - 1.f; }
__device__ __forceinline__ float bf2f(unsigned u) {
    union { unsigned i; float f; } c; c.i = u << 16; return c.f;
}
__device__ __forceinline__ unsigned short f2bf(float f) {
    union { float f; unsigned i; } c; c.f = f;
    unsigned u = c.i + 0x7FFFu + ((c.i >> 16) & 1u);
    return (unsigned short)(u >> 16);
}
__device__ __forceinline__ void gload_lds16(const void* g, void* l) {
    __builtin_amdgcn_global_load_lds(
        (const __attribute__((address_space(1))) void*)(uintptr_t)g,
        (__attribute__((address_space(3))) void*)(unsigned)(uintptr_t)l,
        16, 0, 0);
}

// ---------------- CSR: per-node counting (for exscan) ----------------
__device__ __forceinline__ void count_one(int i, const int* __restrict__ scat_idx,
                                          const int* __restrict__ edge_ix, int* __restrict__ cnt6) {
    if (i < NSETS * NE) {
        int s = i / NE, e = i - s * NE;
        atomicAdd(&cnt6[s * NN + scat_idx[(size_t)s * 2 * NE + NE + e]], 1);
    } else {
        int j = i - NSETS * NE;
        int d = (j < NE) ? edge_ix[NE + j] : (j - NE);
        atomicAdd(&cnt6[5 * NN + d], 1);
    }
}

__global__ void exscan30k(const int* __restrict__ cnt6, int* __restrict__ off6) {
    const int* cnt = cnt6 + blockIdx.x * NN;
    int* off = off6 + blockIdx.x * (NN + 1);
    constexpr int per = 30;
    __shared__ int s[1024];
    const int t = threadIdx.x;
    const int base0 = t * per;
    int sum = 0;
    #pragma unroll
    for (int i = 0; i < per; ++i) { int idx = base0 + i; sum += (idx < NN) ? cnt[idx] : 0; }
    s[t] = sum;
    __syncthreads();
    for (int d = 1; d < 1024; d <<= 1) {
        int v = (t >= d) ? s[t - d] : 0;
        __syncthreads();
        s[t] += v;
        __syncthreads();
    }
    int run = s[t] - sum;
    #pragma unroll
    for (int i = 0; i < per; ++i) {
        int idx = base0 + i;
        if (idx < NN) { off[idx] = run; run += cnt[idx]; }
    }
    if (t == 1023) off[NN] = s[1023];
}

// ---------------- prep1: count | hist | convx | transW | wattk ----------------
#define PREP_CNT_B 2048
#define PREP_CVX_B 1024
#define PREP_TRW_B 512
#define PREP_WAT_B 20
#define PREP_HIST_B NBLK_BIN
#define PREP_GRID (PREP_CNT_B + PREP_CVX_B + PREP_TRW_B + PREP_WAT_B + PREP_HIST_B)

// map hist/bin block index -> (graph, chunk)
__device__ __forceinline__ void chunk_map(int blk, int& g, int& wg, int& e0, int& e1) {
    if (blk < 5 * NWG_SET) { g = blk / NWG_SET; wg = blk - g * NWG_SET; }
    else                   { g = 5;             wg = blk - 5 * NWG_SET; }
    e0 = wg * CHUNK;
    e1 = min(e0 + CHUNK, (g < 5) ? NE : EG);
}

__global__ void prep1(const int* __restrict__ scat_idx, const int* __restrict__ edge_ix,
                      int* __restrict__ cnt6, int* __restrict__ bh,
                      const float* __restrict__ x, unsigned short* __restrict__ xb,
                      const float* __restrict__ lin_W, const float* __restrict__ gat_W,
                      const float* __restrict__ mlp_W,
                      unsigned short* __restrict__ linWT, unsigned short* __restrict__ gatWT,
                      unsigned short* __restrict__ mlpWT,
                      const float* __restrict__ att_src, const float* __restrict__ att_dst,
                      float* __restrict__ watt) {
    __shared__ int h[NBKT];
    const int b = blockIdx.x;
    if (b < PREP_CNT_B) {
        for (int i = b * 256 + threadIdx.x; i < HALFE; i += PREP_CNT_B * 256) {
            count_one(i, scat_idx, edge_ix, cnt6);
            count_one(i + HALFE, scat_idx, edge_ix, cnt6);
        }
    } else if (b < PREP_CNT_B + PREP_CVX_B) {
        const int bb = b - PREP_CNT_B;
        const int total = NN * 512 / 4;
        for (int i = bb * 256 + threadIdx.x; i < total; i += PREP_CVX_B * 256) {
            float4 v = *(const float4*)(x + (size_t)i * 4);
            ushort4 o;
            o.x = f2bf(v.x); o.y = f2bf(v.y); o.z = f2bf(v.z); o.w = f2bf(v.w);
            *(ushort4*)(xb + (size_t)i * 4) = o;
        }
    } else if (b < PREP_CNT_B + PREP_CVX_B + PREP_TRW_B) {
        const int bb = b - PREP_CNT_B - PREP_CVX_B;
        const int total = 65536 + 2 * 327680;
        for (int i = bb * 256 + threadIdx.x; i < total; i += PREP_TRW_B * 256) {
            if (i < 65536) {
                int n = i >> 9, k = i & 511;
                linWT[i] = f2bf(lin_W[(size_t)k * 128 + n]);
            } else if (i < 65536 + 327680) {
                int li = i - 65536;
                int st = li >> 16, r = li & 65535;
                int n = r >> 7, k = r & 127;
                gatWT[li] = f2bf(gat_W[(size_t)st * 65536 + (size_t)k * 512 + n]);
            } else {
                int li = i - 65536 - 327680;
                int st = li >> 16, r = li & 65535;
                int n = r >> 9, k = r & 511;
                mlpWT[li] = f2bf(mlp_W[(size_t)st * 65536 + (size_t)k * 128 + n]);
            }
        }
    } else if (b < PREP_CNT_B + PREP_CVX_B + PREP_TRW_B + PREP_WAT_B) {
        const int tid = (b - PREP_CNT_B - PREP_CVX_B - PREP_TRW_B) * 256 + threadIdx.x;
        if (tid < 5120) {
            int k = tid & 127, hh = (tid >> 7) & 3, tt = (tid >> 9) & 1, i = tid >> 10;
            const float* att = (tt == 0 ? att_src : att_dst) + ((size_t)i * 4 + hh) * 128;
            const float* Wr  = gat_W + ((size_t)i * 128 + k) * 512 + hh * 128;
            float s = 0.f;
            #pragma unroll 8
            for (int c = 0; c < 128; ++c) s = fmaf(Wr[c], att[c], s);
            watt[tid] = s;
        }
    } else {
        // per-(graph,chunk) bucket histogram
        const int blk = b - (PREP_CNT_B + PREP_CVX_B + PREP_TRW_B + PREP_WAT_B);
        int g, wg, e0, e1;
        chunk_map(blk, g, wg, e0, e1);
        for (int i = threadIdx.x; i < NBKT; i += 256) h[i] = 0;
        __syncthreads();
        if (g < 5) {
            const int* dsts = scat_idx + (size_t)g * 2 * NE + NE;
            for (int e = e0 + threadIdx.x; e < e1; e += 256)
                atomicAdd(&h[dsts[e] >> 8], 1);
        } else {
            for (int e = e0 + threadIdx.x; e < e1; e += 256) {
                int d = (e < NE) ? edge_ix[NE + e] : (e - NE);
                atomicAdd(&h[d >> 8], 1);
            }
        }
        __syncthreads();
        for (int i = threadIdx.x; i < NBKT; i += 256)
            bh[(size_t)(g * NBKT + i) * NWGMAX + wg] = h[i];
    }
}

// ---------------- wgscan: per-(graph,bucket) exclusive scan over chunks + CSR base ----------------
__global__ void wgscan(const int* __restrict__ off6, int* __restrict__ bh) {
    const int gb = blockIdx.x;                 // 708
    const int g = gb / NBKT, bk = gb - g * NBKT;
    __shared__ int s[128];
    const int t = threadIdx.x;                 // 128
    const int nwg = (g < 5) ? NWG_SET : NWG_GAT;
    int v = (t < nwg) ? bh[(size_t)gb * NWGMAX + t] : 0;
    s[t] = v;
    __syncthreads();
    for (int d = 1; d < 128; d <<= 1) {
        int u = (t >= d) ? s[t - d] : 0;
        __syncthreads();
        s[t] += u;
        __syncthreads();
    }
    const int base = off6[g * (NN + 1) + (bk << 8)];
    if (t < nwg) bh[(size_t)gb * NWGMAX + t] = base + (s[t] - v);
}

// ---------------- binP: write edges into per-(chunk,bucket) windows (bucket-contiguous staging) ----------------
__global__ void __launch_bounds__(256) binP(const int* __restrict__ scat_idx, const float* __restrict__ scat_w,
                                            const int* __restrict__ edge_ix, const int* __restrict__ pos,
                                            int2* __restrict__ stg_sp, int* __restrict__ stg_g) {
    __shared__ int lpos[NBKT];
    __shared__ int lcur[NBKT];
    int g, wg, e0, e1;
    chunk_map(blockIdx.x, g, wg, e0, e1);
    for (int i = threadIdx.x; i < NBKT; i += 256) {
        lpos[i] = pos[(size_t)(g * NBKT + i) * NWGMAX + wg];
        lcur[i] = 0;
    }
    __syncthreads();
    if (g < 5) {
        const int* si = scat_idx + (size_t)g * 2 * NE;
        const float* sw = scat_w + (size_t)g * NE;
        for (int e = e0 + threadIdx.x; e < e1; e += 256) {
            int src = si[e], d = si[NE + e];
            int r = atomicAdd(&lcur[d >> 8], 1);
            int2 pk; pk.x = src | (d << 15); pk.y = __float_as_int(sw[e]);
            stg_sp[(size_t)g * NE + lpos[d >> 8] + r] = pk;
        }
    } else {
        for (int e = e0 + threadIdx.x; e < e1; e += 256) {
            int src, d;
            if (e < NE) { src = edge_ix[e]; d = edge_ix[NE + e]; }
            else        { src = e - NE;     d = src; }
            int r = atomicAdd(&lcur[d >> 8], 1);
            stg_g[lpos[d >> 8] + r] = src | (d << 15);
        }
    }
}

// ---------------- sortP: per-bucket L2-local per-node scatter into final CSR ----------------
__global__ void __launch_bounds__(256) sortP(const int* __restrict__ off6,
                                             const int2* __restrict__ stg_sp, const int* __restrict__ stg_g,
                                             int2* __restrict__ spp, int* __restrict__ g_src) {
    __shared__ int loff[257];
    __shared__ int lcur[256];
    const int gb = blockIdx.x;
    const int g = gb / NBKT, bk = gb - g * NBKT;
    const int n0 = bk << 8;
    const int nlen = min(256, NN - n0);
    const int* offg = off6 + g * (NN + 1);
    for (int i = threadIdx.x; i < 257; i += 256) loff[i] = offg[min(n0 + i, NN)];
    for (int i = threadIdx.x; i < 256; i += 256) lcur[i] = 0;
    __syncthreads();
    const int s0 = loff[0], s1 = loff[nlen];
    if (g < 5) {
        for (int j = s0 + threadIdx.x; j < s1; j += 256) {
            int2 pk = stg_sp[(size_t)g * NE + j];
            int ln = ((pk.x >> 15) & 0x7fff) - n0;
            int p = loff[ln] + atomicAdd(&lcur[ln], 1);
            int2 o; o.x = pk.x & 0x7fff; o.y = pk.y;
            spp[(size_t)g * NE + p] = o;
        }
    } else {
        for (int j = s0 + threadIdx.x; j < s1; j += 256) {
            int w = stg_g[j];
            int ln = ((w >> 15) & 0x7fff) - n0;
            int p = loff[ln] + atomicAdd(&lcur[ln], 1);
            g_src[p] = w & 0x7fff;
        }
    }
}

// ---------------- staging helper for MFMA GEMMs ----------------
template<int ROWS>
__device__ __forceinline__ void stage64(const unsigned short* __restrict__ src, int ld,
                                        int row0, int maxrow, int k0, char* lds, int t) {
    const int wave = t >> 6, lane = t & 63;
    const int sub = lane >> 3;
    const int kch = (lane & 7) ^ sub;
    for (int j = wave; j < ROWS / 8; j += 4) {
        int grow = row0 + j * 8 + sub;
        if (grow > maxrow) grow = maxrow;
        gload_lds16(src + (size_t)grow * ld + k0 + kch * 8, lds + j * 1024);
    }
}

// ---------------- MFMA bf16 GEMM (LIN) ----------------
__global__ void __launch_bounds__(256) mgemm_lin(const unsigned short* __restrict__ A,
                                                 const unsigned short* __restrict__ BT,
                                                 const float* __restrict__ bias,
                                                 unsigned short* __restrict__ outb,
                                                 float* __restrict__ x2) {
    constexpr int K = 512, NC = 128;
    __shared__ __align__(16) char As[64 * 128];
    __shared__ __align__(16) char Bs[128 * 128];
    const int t = threadIdx.x, wave = t >> 6, lane = t & 63;
    const int bm = blockIdx.x * 64;
    const int wr = (wave >> 1) * 32, wc = (wave & 1) * 64;
    const int l15 = lane & 15, l4 = lane >> 4;
    const int rsw = (l15 & 7) << 4;
    f32x4 acc[2][4] = {};

    for (int kt = 0; kt < K; kt += 64) {
        stage64<64>(A, K, bm, NN - 1, kt, As, t);
        stage64<128>(BT, K, 0, NC - 1, kt, Bs, t);
        __syncthreads();
        #pragma unroll
        for (int kk = 0; kk < 2; ++kk) {
            bf16x8 af[2], bf[4];
            const int koff = kk * 64 + l4 * 16;
            #pragma unroll
            for (int fm = 0; fm < 2; ++fm)
                af[fm] = *(const bf16x8*)(As + (wr + fm * 16 + l15) * 128 + (koff ^ rsw));
            #pragma unroll
            for (int fn = 0; fn < 4; ++fn)
                bf[fn] = *(const bf16x8*)(Bs + (wc + fn * 16 + l15) * 128 + (koff ^ rsw));
            #pragma unroll
            for (int fm = 0; fm < 2; ++fm)
                #pragma unroll
                for (int fn = 0; fn < 4; ++fn)
                    acc[fm][fn] = __builtin_amdgcn_mfma_f32_16x16x32_bf16(af[fm], bf[fn], acc[fm][fn], 0, 0, 0);
        }
        __syncthreads();
    }

    #pragma unroll
    for (int fn = 0; fn < 4; ++fn) {
        const int c = wc + fn * 16 + l15;
        const float bias_c = bias[c];
        #pragma unroll
        for (int fm = 0; fm < 2; ++fm) {
            #pragma unroll
            for (int rg = 0; rg < 4; ++rg) {
                int r = bm + wr + fm * 16 + l4 * 4 + rg;
                if (r < NN) {
                    float v = acc[fm][fn][rg] + bias_c;
                    outb[(size_t)r * NC + c] = f2bf(v);
                    x2[(size_t)r * NC + c] = v;
                }
            }
        }
    }
}

// ---------------- fused GATELU + MLP + BN-accumulate ----------------
__global__ void __launch_bounds__(256) fusedGM(const unsigned short* __restrict__ agg,
                                               const unsigned short* __restrict__ gatWT,
                                               const unsigned short* __restrict__ mlpWT,
                                               const float* __restrict__ gat_b,
                                               const float* __restrict__ mlp_b,
                                               const float* __restrict__ bng, const float* __restrict__ bnb,
                                               const float* __restrict__ bnm, const float* __restrict__ bnv,
                                               float* __restrict__ x2) {
    __shared__ __align__(16) char U[49152];
    __shared__ __align__(16) char gtile[16384];
    const int t = threadIdx.x, wave = t >> 6, lane = t & 63;
    const int bm = blockIdx.x * 64;
    const int wr = (wave >> 1) * 32, wc = (wave & 1) * 64;
    const int l15 = lane & 15, l4 = lane >> 4;
    const int rsw = (l15 & 7) << 4;
    f32x4 acc2[2][4] = {};

    #pragma unroll
    for (int h = 0; h < 4; ++h) {
        stage64<64>(agg, 512, bm, NN - 1, h * 128,       U,         t);
        stage64<64>(agg, 512, bm, NN - 1, h * 128 + 64,  U + 8192,  t);
        stage64<128>(gatWT, 128, h * 128, 511, 0,        U + 16384, t);
        stage64<128>(gatWT, 128, h * 128, 511, 64,       U + 32768, t);
        __syncthreads();

        f32x4 a1[2][4] = {};
        #pragma unroll
        for (int ks = 0; ks < 4; ++ks) {
            const char* Asb = U + (ks >> 1) * 8192;
            const char* Bsb = U + 16384 + (ks >> 1) * 16384;
            const int koff = (ks & 1) * 64 + l4 * 16;
            bf16x8 af[2], bf[4];
            #pragma unroll
            for (int fm = 0; fm < 2; ++fm)
                af[fm] = *(const bf16x8*)(Asb + (wr + fm * 16 + l15) * 128 + (koff ^ rsw));
            #pragma unroll
            for (int fn = 0; fn < 4; ++fn)
                bf[fn] = *(const bf16x8*)(Bsb + (wc + fn * 16 + l15) * 128 + (koff ^ rsw));
            #pragma unroll
            for (int fm = 0; fm < 2; ++fm)
                #pragma unroll
                for (int fn = 0; fn < 4; ++fn)
                    a1[fm][fn] = __builtin_amdgcn_mfma_f32_16x16x32_bf16(af[fm], bf[fn], a1[fm][fn], 0, 0, 0);
        }
        __syncthreads();

        #pragma unroll
        for (int fn = 0; fn < 4; ++fn) {
            const int cc = wc + fn * 16 + l15;
            const float gb = gat_b[h * 128 + cc];
            #pragma unroll
            for (int fm = 0; fm < 2; ++fm) {
                #pragma unroll
                for (int rg = 0; rg < 4; ++rg) {
                    const int r = wr + fm * 16 + l4 * 4 + rg;
                    const unsigned short v = f2bf(eluf(a1[fm][fn][rg] + gb));
                    *(unsigned short*)(gtile + r * 256 + ((((cc >> 3) ^ (r & 7)) << 4) | ((cc & 7) << 1))) = v;
                }
            }
        }
        stage64<128>(mlpWT, 512, 0, 127, h * 128,      U,         t);
        stage64<128>(mlpWT, 512, 0, 127, h * 128 + 64, U + 16384, t);
        __syncthreads();

        #pragma unroll
        for (int ks = 0; ks < 4; ++ks) {
            const int s2 = ks >> 1, kk = ks & 1;
            const char* slab = U + s2 * 16384;
            bf16x8 af[2], bf[4];
            #pragma unroll
            for (int fm = 0; fm < 2; ++fm) {
                const int r2 = wr + fm * 16 + l15;
                const int chunk = (s2 * 8 + kk * 4 + l4) ^ (r2 & 7);
                af[fm] = *(const bf16x8*)(gtile + r2 * 256 + (chunk << 4));
            }
            const int koff = kk * 64 + l4 * 16;
            #pragma unroll
            for (int fn = 0; fn < 4; ++fn)
                bf[fn] = *(const bf16x8*)(slab + (wc + fn * 16 + l15) * 128 + (koff ^ rsw));
            #pragma unroll
            for (int fm = 0; fm < 2; ++fm)
                #pragma unroll
                for (int fn = 0; fn < 4; ++fn)
                    acc2[fm][fn] = __builtin_amdgcn_mfma_f32_16x16x32_bf16(af[fm], bf[fn], acc2[fm][fn], 0, 0, 0);
        }
        __syncthreads();
    }

    #pragma unroll
    for (int fn = 0; fn < 4; ++fn) {
        const int c = wc + fn * 16 + l15;
        const float sc = bng[c] * rsqrtf(bnv[c] + BN_EPS);
        const float sh = bnb[c] - bnm[c] * sc;
        const float mb = mlp_b[c];
        #pragma unroll
        for (int fm = 0; fm < 2; ++fm) {
            #pragma unroll
            for (int rg = 0; rg < 4; ++rg) {
                int r = bm + wr + fm * 16 + l4 * 4 + rg;
                if (r < NN)
                    x2[(size_t)r * 128 + c] += (acc2[fm][fn][rg] + mb) * sc + sh;
            }
        }
    }
}

// ---------------- phase 0: tmp_y = abs(sp(y+1, hb)), 8-way edge unroll ----------------
__global__ void __launch_bounds__(256) sp_abs4(const int* __restrict__ off6,
                                               const int2* __restrict__ spp,
                                               const unsigned short* __restrict__ hb,
                                               unsigned short* __restrict__ tmp4) {
    const int y = blockIdx.y;
    const int* off = off6 + (y + 1) * (NN + 1);
    const int2* pk = spp + (size_t)(y + 1) * NE;
    unsigned short* out = tmp4 + (size_t)y * NN * 128;

    const int wid  = blockIdx.x * 4 + (threadIdx.x >> 6);
    const int lane = threadIdx.x & 63;
    const int co   = lane * 2;
    const int s0 = off[wid], s1 = off[wid + 1];
    float a0 = 0.f, a1 = 0.f;
    int j = s0;
    for (; j + 7 < s1; j += 8) {
        int2 e[8];
        unsigned v[8];
        #pragma unroll
        for (int q = 0; q < 8; ++q) e[q] = pk[j + q];
        #pragma unroll
        for (int q = 0; q < 8; ++q) v[q] = *(const unsigned*)(hb + (size_t)e[q].x * 128 + co);
        #pragma unroll
        for (int q = 0; q < 8; ++q) {
            float w = __int_as_float(e[q].y);
            a0 = fmaf(w, bf2f(v[q] & 0xffffu), a0);
            a1 = fmaf(w, bf2f(v[q] >> 16), a1);
        }
    }
    for (; j < s1; ++j) {
        int2 e = pk[j];
        float wj = __int_as_float(e.y);
        unsigned v = *(const unsigned*)(hb + (size_t)e.x * 128 + co);
        a0 = fmaf(wj, bf2f(v & 0xffffu), a0);
        a1 = fmaf(wj, bf2f(v >> 16), a1);
    }
    a0 = fabsf(a0); a1 = fabsf(a1);
    unsigned o = (unsigned)f2bf(a0) | ((unsigned)f2bf(a1) << 16);
    *(unsigned*)(out + (size_t)wid * 128 + co) = o;
}

// ---------------- phase 1: xcur_y = sp(0, {hb,tmp0..3}) fused + attention scores ----------------
__global__ void __launch_bounds__(256) sp_fused5(const int* __restrict__ off0,
                                                 const int2* __restrict__ spp0,
                                                 const unsigned short* __restrict__ hb,
                                                 const unsigned short* __restrict__ tmp4,
                                                 unsigned short* __restrict__ xcur5,
                                                 const float* __restrict__ watt,
                                                 float* __restrict__ as5,
                                                 float* __restrict__ ad5) {
    __shared__ float sWatt[5120];
    for (int i = threadIdx.x; i < 5120; i += 256) sWatt[i] = watt[i];
    __syncthreads();

    const int wid  = blockIdx.x * 4 + (threadIdx.x >> 6);
    const int lane = threadIdx.x & 63;
    const int co   = lane * 2;
    const int s0 = off0[wid], s1 = off0[wid + 1];
    const unsigned short* t0 = tmp4;
    const unsigned short* t1 = tmp4 + (size_t)1 * NN * 128;
    const unsigned short* t2 = tmp4 + (size_t)2 * NN * 128;
    const unsigned short* t3 = tmp4 + (size_t)3 * NN * 128;

    float a[5][2] = {};
    int j = s0;
    for (; j + 1 < s1; j += 2) {
        int2 eA = spp0[j], eB = spp0[j + 1];
        size_t rA = (size_t)eA.x * 128 + co, rB = (size_t)eB.x * 128 + co;
        unsigned vA0 = *(const unsigned*)(hb + rA), vB0 = *(const unsigned*)(hb + rB);
        unsigned vA1 = *(const unsigned*)(t0 + rA), vB1 = *(const unsigned*)(t0 + rB);
        unsigned vA2 = *(const unsigned*)(t1 + rA), vB2 = *(const unsigned*)(t1 + rB);
        unsigned vA3 = *(const unsigned*)(t2 + rA), vB3 = *(const unsigned*)(t2 + rB);
        unsigned vA4 = *(const unsigned*)(t3 + rA), vB4 = *(const unsigned*)(t3 + rB);
        float wA = __int_as_float(eA.y), wB = __int_as_float(eB.y);
        a[0][0] = fmaf(wA, bf2f(vA0 & 0xffffu), a[0][0]); a[0][1] = fmaf(wA, bf2f(vA0 >> 16), a[0][1]);
        a[1][0] = fmaf(wA, bf2f(vA1 & 0xffffu), a[1][0]); a[1][1] = fmaf(wA, bf2f(vA1 >> 16), a[1][1]);
        a[2][0] = fmaf(wA, bf2f(vA2 & 0xffffu), a[2][0]); a[2][1] = fmaf(wA, bf2f(vA2 >> 16), a[2][1]);
        a[3][0] = fmaf(wA, bf2f(vA3 & 0xffffu), a[3][0]); a[3][1] = fmaf(wA, bf2f(vA3 >> 16), a[3][1]);
        a[4][0] = fmaf(wA, bf2f(vA4 & 0xffffu), a[4][0]); a[4][1] = fmaf(wA, bf2f(vA4 >> 16), a[4][1]);
        a[0][0] = fmaf(wB, bf2f(vB0 & 0xffffu), a[0][0]); a[0][1] = fmaf(wB, bf2f(vB0 >> 16), a[0][1]);
        a[1][0] = fmaf(wB, bf2f(vB1 & 0xffffu), a[1][0]); a[1][1] = fmaf(wB, bf2f(vB1 >> 16), a[1][1]);
        a[2][0] = fmaf(wB, bf2f(vB2 & 0xffffu), a[2][0]); a[2][1] = fmaf(wB, bf2f(vB2 >> 16), a[2][1]);
        a[3][0] = fmaf(wB, bf2f(vB3 & 0xffffu), a[3][0]); a[3][1] = fmaf(wB, bf2f(vB3 >> 16), a[3][1]);
        a[4][0] = fmaf(wB, bf2f(vB4 & 0xffffu), a[4][0]); a[4][1] = fmaf(wB, bf2f(vB4 >> 16), a[4][1]);
    }
    if (j < s1) {
        int2 e = spp0[j];
        size_t r = (size_t)e.x * 128 + co;
        unsigned v0 = *(const unsigned*)(hb + r);
        unsigned v1 = *(const unsigned*)(t0 + r);
        unsigned v2 = *(const unsigned*)(t1 + r);
        unsigned v3 = *(const unsigned*)(t2 + r);
        unsigned v4 = *(const unsigned*)(t3 + r);
        float wj = __int_as_float(e.y);
        a[0][0] = fmaf(wj, bf2f(v0 & 0xffffu), a[0][0]); a[0][1] = fmaf(wj, bf2f(v0 >> 16), a[0][1]);
        a[1][0] = fmaf(wj, bf2f(v1 & 0xffffu), a[1][0]); a[1][1] = fmaf(wj, bf2f(v1 >> 16), a[1][1]);
        a[2][0] = fmaf(wj, bf2f(v2 & 0xffffu), a[2][0]); a[2][1] = fmaf(wj, bf2f(v2 >> 16), a[2][1]);
        a[3][0] = fmaf(wj, bf2f(v3 & 0xffffu), a[3][0]); a[3][1] = fmaf(wj, bf2f(v3 >> 16), a[3][1]);
        a[4][0] = fmaf(wj, bf2f(v4 & 0xffffu), a[4][0]); a[4][1] = fmaf(wj, bf2f(v4 >> 16), a[4][1]);
    }
    #pragma unroll
    for (int y = 0; y < 5; ++y) {
        unsigned o = (unsigned)f2bf(a[y][0]) | ((unsigned)f2bf(a[y][1]) << 16);
        *(unsigned*)(xcur5 + (size_t)y * NN * 128 + (size_t)wid * 128 + co) = o;
    }

    #pragma unroll
    for (int i = 0; i < 5; ++i) {
        #pragma unroll
        for (int h = 0; h < 4; ++h) {
            const float* wS = sWatt + ((i * 2 + 0) * 4 + h) * 128;
            const float* wD = sWatt + ((i * 2 + 1) * 4 + h) * 128;
            float ps = a[i][0] * wS[co] + a[i][1] * wS[co + 1];
            float pd = a[i][0] * wD[co] + a[i][1] * wD[co + 1];
            #pragma unroll
            for (int dd = 1; dd < 64; dd <<= 1) { ps += __shfl_xor(ps, dd); pd += __shfl_xor(pd, dd); }
            if (lane == 0) {
                as5[(size_t)i * NN * 4 + (size_t)wid * 4 + h] = ps;
                ad5[(size_t)i * NN * 4 + (size_t)wid * 4 + h] = pd;
            }
        }
    }
}

// ---------------- GAT aggregation on xcur (pre-W) ----------------
__device__ __forceinline__ void acc8(float* a, float al, uint4 v) {
    a[0] = fmaf(al, bf2f(v.x & 0xffffu), a[0]); a[1] = fmaf(al, bf2f(v.x >> 16), a[1]);
    a[2] = fmaf(al, bf2f(v.y & 0xffffu), a[2]); a[3] = fmaf(al, bf2f(v.y >> 16), a[3]);
    a[4] = fmaf(al, bf2f(v.z & 0xffffu), a[4]); a[5] = fmaf(al, bf2f(v.z >> 16), a[5]);
    a[6] = fmaf(al, bf2f(v.w & 0xffffu), a[6]); a[7] = fmaf(al, bf2f(v.w >> 16), a[7]);
}

__global__ void __launch_bounds__(256) gat_agg2(const int* __restrict__ goff, const int* __restrict__ gsrc,
                                                const float* __restrict__ as_, const float* __restrict__ ad_,
                                                const unsigned short* __restrict__ xcur,
                                                unsigned short* __restrict__ agg) {
    const int wid  = blockIdx.x * 4 + (threadIdx.x >> 6);
    const int lane = threadIdx.x & 63;
    const int hd   = lane >> 4;
    const int cl   = (lane & 15) * 8;
    const int s0 = goff[wid], s1 = goff[wid + 1];
    const float4 adv4 = *(const float4*)(ad_ + (size_t)wid * 4);

    float m[4] = {-1e30f, -1e30f, -1e30f, -1e30f};
    float s[4] = {0.f, 0.f, 0.f, 0.f};
    for (int j = s0 + lane; j < s1; j += 64) {
        const int si = gsrc[j];
        float4 av = *(const float4*)(as_ + (size_t)si * 4);
        float e[4] = {lrelu02(av.x + adv4.x), lrelu02(av.y + adv4.y),
                      lrelu02(av.z + adv4.z), lrelu02(av.w + adv4.w)};
        #pragma unroll
        for (int h = 0; h < 4; ++h) {
            if (e[h] > m[h]) { s[h] = s[h] * __expf(m[h] - e[h]) + 1.f; m[h] = e[h]; }
            else             { s[h] += __expf(e[h] - m[h]); }
        }
    }
    #pragma unroll
    for (int d = 1; d < 64; d <<= 1) {
        #pragma unroll
        for (int h = 0; h < 4; ++h) {
            float om = __shfl_xor(m[h], d);
            float os = __shfl_xor(s[h], d);
            float nm = fmaxf(m[h], om);
            s[h] = s[h] * __expf(m[h] - nm) + os * __expf(om - nm);
            m[h] = nm;
        }
    }
    const float advh = hd == 0 ? adv4.x : hd == 1 ? adv4.y : hd == 2 ? adv4.z : adv4.w;
    const float mv   = hd == 0 ? m[0]   : hd == 1 ? m[1]   : hd == 2 ? m[2]   : m[3];
    const float dv   = hd == 0 ? s[0]   : hd == 1 ? s[1]   : hd == 2 ? s[2]   : s[3];
    const float inv  = 1.f / (dv + 1e-16f);

    float ac[8] = {};
    int j = s0;
    for (; j + 1 < s1; j += 2) {
        int i0 = gsrc[j], i1 = gsrc[j + 1];
        float q0 = as_[(size_t)i0 * 4 + hd], q1 = as_[(size_t)i1 * 4 + hd];
        uint4 v0 = *(const uint4*)(xcur + (size_t)i0 * 128 + cl);
        uint4 v1 = *(const uint4*)(xcur + (size_t)i1 * 128 + cl);
        float al0 = __expf(lrelu02(q0 + advh) - mv) * inv;
        float al1 = __expf(lrelu02(q1 + advh) - mv) * inv;
        acc8(ac, al0, v0); acc8(ac, al1, v1);
    }
    if (j < s1) {
        int si = gsrc[j];
        float q = as_[(size_t)si * 4 + hd];
        uint4 v = *(const uint4*)(xcur + (size_t)si * 128 + cl);
        float al = __expf(lrelu02(q + advh) - mv) * inv;
        acc8(ac, al, v);
    }
    uint4 ov;
    ov.x = (unsigned)f2bf(ac[0]) | ((unsigned)f2bf(ac[1]) << 16);
    ov.y = (unsigned)f2bf(ac[2]) | ((unsigned)f2bf(ac[3]) << 16);
    ov.z = (unsigned)f2bf(ac[4]) | ((unsigned)f2bf(ac[5]) << 16);
    ov.w = (unsigned)f2bf(ac[6]) | ((unsigned)f2bf(ac[7]) << 16);
    *(uint4*)(agg + (size_t)wid * 512 + hd * 128 + cl) = ov;
}

// ---------------- final ----------------
__global__ void __launch_bounds__(256) final_out(const float* __restrict__ x2,
                                                 const float* __restrict__ bn0g, const float* __restrict__ bn0b,
                                                 const float* __restrict__ bn0m, const float* __restrict__ bn0v,
                                                 const float* __restrict__ outW, const float* __restrict__ outb,
                                                 float* __restrict__ out) {
    __shared__ float sW[128 * 12];
    __shared__ float sSc[128], sSh[128];
    for (int i = threadIdx.x; i < 1280; i += 256) {
        int r = i / 10, c = i - r * 10;
        sW[r * 12 + c] = outW[i];
    }
    if (threadIdx.x < 128) {
        int c = threadIdx.x;
        float sc = bn0g[c] * rsqrtf(bn0v[c] + BN_EPS);
        sSc[c] = sc;
        sSh[c] = bn0b[c] - bn0m[c] * sc;
    }
    __syncthreads();
    const int wid  = blockIdx.x * 4 + (threadIdx.x >> 6);
    const int lane = threadIdx.x & 63;
    const int c0 = lane * 2;
    float2 a = *(const float2*)(x2 + (size_t)wid * 128 + c0);
    float a0 = eluf(a.x * sSc[c0] + sSh[c0]);
    float a1 = eluf(a.y * sSc[c0 + 1] + sSh[c0 + 1]);
    float p[NCLS];
    #pragma unroll
    for (int j = 0; j < NCLS; ++j)
        p[j] = a0 * sW[c0 * 12 + j] + a1 * sW[(c0 + 1) * 12 + j];
    #pragma unroll
    for (int j = 0; j < NCLS; ++j) {
        float v = p[j];
        v += __shfl_xor(v, 1);  v += __shfl_xor(v, 2);  v += __shfl_xor(v, 4);
        v += __shfl_xor(v, 8);  v += __shfl_xor(v, 16); v += __shfl_xor(v, 32);
        p[j] = v;
    }
    float z[NCLS];
    #pragma unroll
    for (int j = 0; j < NCLS; ++j) z[j] = p[j] + outb[j];
    float m = z[0];
    #pragma unroll
    for (int j = 1; j < NCLS; ++j) m = fmaxf(m, z[j]);
    float ssum = 0.f;
    #pragma unroll
    for (int j = 0; j < NCLS; ++j) ssum += __expf(z[j] - m);
    float lse = m + __logf(ssum);
    #pragma unroll
    for (int j = 0; j < NCLS; ++j)
        if (lane == j) out[(size_t)wid * NCLS + j] = z[j] - lse;
}

// ---------------- launcher ----------------
extern "C" void kernel_launch(void* const* d_in, const int* in_sizes, int n_in,
                              void* d_out, int out_size, void* d_ws, size_t ws_size,
                              hipStream_t stream) {
    const float* x        = (const float*)d_in[0];
    const int*   edge_ix  = (const int*)  d_in[1];
    const int*   scat_idx = (const int*)  d_in[2];
    const float* scat_w   = (const float*)d_in[3];
    const float* lin_W    = (const float*)d_in[4];
    const float* lin_b    = (const float*)d_in[5];
    const float* gat_W    = (const float*)d_in[6];
    const float* att_src  = (const float*)d_in[7];
    const float* att_dst  = (const float*)d_in[8];
    const float* gat_b    = (const float*)d_in[9];
    const float* mlp_W    = (const float*)d_in[10];
    const float* mlp_b    = (const float*)d_in[11];
    const float* bn_g     = (const float*)d_in[12];
    const float* bn_b     = (const float*)d_in[13];
    const float* bn_m     = (const float*)d_in[14];
    const float* bn_v     = (const float*)d_in[15];
    const float* bn0_g    = (const float*)d_in[16];
    const float* bn0_b    = (const float*)d_in[17];
    const float* bn0_m    = (const float*)d_in[18];
    const float* bn0_v    = (const float*)d_in[19];
    const float* out_W    = (const float*)d_in[20];
    const float* out_b    = (const float*)d_in[21];
    float* out = (float*)d_out;

    char* ws = (char*)d_ws;
    unsigned short* xb    = (unsigned short*)(ws + OFF_U1);
    unsigned short* xcur5 = (unsigned short*)(ws + OFF_U1);
    unsigned short* hb    = (unsigned short*)(ws + OFF_HB);
    float*          x2    = (float*)(ws + OFF_X2);
    unsigned short* agg   = (unsigned short*)(ws + OFF_AGG);
    unsigned short* tmp4  = (unsigned short*)(ws + OFF_GOUT);
    int2*  stg_sp = (int2*)(ws + OFF_GOUT);                           // staging (dead before tmp4 use)
    int*   stg_g  = (int*)(ws + OFF_GOUT + (size_t)NSETS * NE * 8);
    unsigned short* wt    = (unsigned short*)(ws + OFF_WT);
    unsigned short* linWT = wt;
    unsigned short* gatWT = wt + 65536;
    unsigned short* mlpWT = wt + 65536 * 6;
    float* watt   = (float*)(ws + OFF_WATT);
    int*   off6   = (int*)(ws + OFF_OFF6);
    int2*  spp    = (int2*)(ws + OFF_SPP);
    int*   g_src  = (int*)(ws + OFF_GSRC);
    int*   cnt6   = (int*)(ws + OFF_CNT);
    int*   bh     = cnt6 + 6 * NN;          // [708][105] chunk histograms / positions
    float* as5    = (float*)(ws + OFF_AS5);
    float* ad5    = (float*)(ws + OFF_AD5);

    const dim3 b256(256);

    // ---- CSR build: count+hist (prep1) -> node scan -> chunk scan -> bin -> bucket sort ----
    hipMemsetAsync(cnt6, 0, (size_t)6 * NN * 4, stream);
    prep1<<<PREP_GRID, b256, 0, stream>>>(scat_idx, edge_ix, cnt6, bh, x, xb,
                                          lin_W, gat_W, mlp_W, linWT, gatWT, mlpWT,
                                          att_src, att_dst, watt);
    exscan30k<<<6, 1024, 0, stream>>>(cnt6, off6);
    wgscan<<<NBLK_SORT, 128, 0, stream>>>(off6, bh);
    binP<<<NBLK_BIN, b256, 0, stream>>>(scat_idx, scat_w, edge_ix, bh, stg_sp, stg_g);
    sortP<<<NBLK_SORT, b256, 0, stream>>>(off6, stg_sp, stg_g, spp, g_src);

    // ---- h = x @ lin_W + lin_b ; x2 = h ----
    mgemm_lin<<<469, b256, 0, stream>>>(xb, linWT, lin_b, hb, x2);

    // ---- solo passes (+ fused attention scores) ----
    sp_abs4<<<dim3(7500, 4), b256, 0, stream>>>(off6, spp, hb, tmp4);
    sp_fused5<<<7500, b256, 0, stream>>>(off6, spp, hb, tmp4, xcur5, watt, as5, ad5);

    // ---- 5 GAT branches ----
    for (int i = 0; i < NSETS; ++i) {
        gat_agg2<<<7500, b256, 0, stream>>>(off6 + 5 * (NN + 1), g_src,
                                            as5 + (size_t)i * NN * 4, ad5 + (size_t)i * NN * 4,
                                            xcur5 + (size_t)i * NN * 128, agg);
        fusedGM<<<469, b256, 0, stream>>>(agg, gatWT + (size_t)i * 65536, mlpWT + (size_t)i * 65536,
                                          gat_b + (size_t)i * 512, mlp_b + (size_t)i * 128,
                                          bn_g + (size_t)i * 128, bn_b + (size_t)i * 128,
                                          bn_m + (size_t)i * 128, bn_v + (size_t)i * 128, x2);
    }

    // ---- final ----
    final_out<<<7500, b256, 0, stream>>>(x2, bn0_g, bn0_b, bn0_m, bn0_v, out_W, out_b, out);
}

// Round 9
// 680.358 us; speedup vs baseline: 3.4356x; 1.2069x over previous
//
#include <hip/hip_runtime.h>
#include <cstdint>
#include <cstddef>

// ---------------- problem constants ----------------
#define NN 30000        // nodes
#define NE 400000       // edges per scatter set
#define EG (NE + NN)    // GAT edges incl self loops
#define NSETS 5
#define NCLS 10
#define BN_EPS 1e-5f

// bucketed CSR build
#define NBKT 118        // buckets of 256 dst nodes
#define CHUNK 4096
#define NWG_SET 98      // ceil(400000/4096)
#define NWG_GAT 105     // ceil(430000/4096)
#define NWGMAX 105
#define NBLK_BIN (5 * NWG_SET + NWG_GAT)   // 595
#define NBLK_SORT (6 * NBKT)               // 708

typedef __bf16 bf16x8 __attribute__((ext_vector_type(8)));
typedef float  f32x4  __attribute__((ext_vector_type(4)));

// ---------------- workspace layout (bytes) ----------------
constexpr size_t alg(size_t x) { return (x + 255) & ~size_t(255); }
constexpr size_t OFF_U1    = 0;                                        // xb | xcur5
constexpr size_t OFF_HB    = OFF_U1   + alg((size_t)5 * NN * 128 * 2);
constexpr size_t OFF_X2    = OFF_HB   + alg((size_t)NN * 128 * 2);
constexpr size_t OFF_AGG   = OFF_X2   + alg((size_t)NN * 128 * 4);
constexpr size_t OFF_GOUT  = OFF_AGG  + alg((size_t)NN * 512 * 2);     // CSR staging -> tmp4
constexpr size_t OFF_WT    = OFF_GOUT + alg((size_t)NN * 512 * 2);
constexpr size_t OFF_WATT  = OFF_WT   + alg((size_t)11 * 65536 * 2);
constexpr size_t OFF_OFF6  = OFF_WATT + alg((size_t)5 * 2 * 4 * 128 * 4);
constexpr size_t OFF_SPP   = OFF_OFF6 + alg((size_t)6 * (NN + 1) * 4);
constexpr size_t OFF_GSRC  = OFF_SPP  + alg((size_t)NSETS * NE * 8);
constexpr size_t OFF_CNT   = OFF_GSRC + alg((size_t)EG * 4);
constexpr size_t OFF_AS5   = OFF_CNT  + alg((size_t)12 * NN * 4);
constexpr size_t OFF_AD5   = OFF_AS5  + alg((size_t)5 * NN * 4 * 4);
constexpr size_t WS_NEED   = OFF_AD5  + alg((size_t)5 * NN * 4 * 4);   // ~149 MB

// ---------------- helpers ----------------
__device__ __forceinline__ float lrelu02(float v) { return v > 0.f ? v : 0.2f * v; }
__device__ __forceinline__ float eluf(float v)    { return v > 0.f ? v : __expf(v) - 1.f; }
__device__ __forceinline__ float bf2f(unsigned u) {
    union { unsigned i; float f; } c; c.i = u << 16; return c.f;
}
__device__ __forceinline__ unsigned short f2bf(float f) {
    union { float f; unsigned i; } c; c.f = f;
    unsigned u = c.i + 0x7FFFu + ((c.i >> 16) & 1u);
    return (unsigned short)(u >> 16);
}
__device__ __forceinline__ void gload_lds16(const void* g, void* l) {
    __builtin_amdgcn_global_load_lds(
        (const __attribute__((address_space(1))) void*)(uintptr_t)g,
        (__attribute__((address_space(3))) void*)(unsigned)(uintptr_t)l,
        16, 0, 0);
}

// map hist/bin block index -> (graph, chunk)
__device__ __forceinline__ void chunk_map(int blk, int& g, int& wg, int& e0, int& e1) {
    if (blk < 5 * NWG_SET) { g = blk / NWG_SET; wg = blk - g * NWG_SET; }
    else                   { g = 5;             wg = blk - 5 * NWG_SET; }
    e0 = wg * CHUNK;
    e1 = min(e0 + CHUNK, (g < 5) ? NE : EG);
}

// ---------------- prep1: hist | convx | transW | wattk  (NO per-node counting) ----------------
#define PREP_CVX_B 1024
#define PREP_TRW_B 512
#define PREP_WAT_B 20
#define PREP_HIST_B NBLK_BIN
#define PREP_GRID (PREP_CVX_B + PREP_TRW_B + PREP_WAT_B + PREP_HIST_B)

__global__ void prep1(const int* __restrict__ scat_idx, const int* __restrict__ edge_ix,
                      int* __restrict__ bh,
                      const float* __restrict__ x, unsigned short* __restrict__ xb,
                      const float* __restrict__ lin_W, const float* __restrict__ gat_W,
                      const float* __restrict__ mlp_W,
                      unsigned short* __restrict__ linWT, unsigned short* __restrict__ gatWT,
                      unsigned short* __restrict__ mlpWT,
                      const float* __restrict__ att_src, const float* __restrict__ att_dst,
                      float* __restrict__ watt) {
    __shared__ int h[NBKT];
    const int b = blockIdx.x;
    if (b < PREP_CVX_B) {
        const int total = NN * 512 / 4;
        for (int i = b * 256 + threadIdx.x; i < total; i += PREP_CVX_B * 256) {
            float4 v = *(const float4*)(x + (size_t)i * 4);
            ushort4 o;
            o.x = f2bf(v.x); o.y = f2bf(v.y); o.z = f2bf(v.z); o.w = f2bf(v.w);
            *(ushort4*)(xb + (size_t)i * 4) = o;
        }
    } else if (b < PREP_CVX_B + PREP_TRW_B) {
        const int bb = b - PREP_CVX_B;
        const int total = 65536 + 2 * 327680;
        for (int i = bb * 256 + threadIdx.x; i < total; i += PREP_TRW_B * 256) {
            if (i < 65536) {
                int n = i >> 9, k = i & 511;
                linWT[i] = f2bf(lin_W[(size_t)k * 128 + n]);
            } else if (i < 65536 + 327680) {
                int li = i - 65536;
                int st = li >> 16, r = li & 65535;
                int n = r >> 7, k = r & 127;
                gatWT[li] = f2bf(gat_W[(size_t)st * 65536 + (size_t)k * 512 + n]);
            } else {
                int li = i - 65536 - 327680;
                int st = li >> 16, r = li & 65535;
                int n = r >> 9, k = r & 511;
                mlpWT[li] = f2bf(mlp_W[(size_t)st * 65536 + (size_t)k * 128 + n]);
            }
        }
    } else if (b < PREP_CVX_B + PREP_TRW_B + PREP_WAT_B) {
        const int tid = (b - PREP_CVX_B - PREP_TRW_B) * 256 + threadIdx.x;
        if (tid < 5120) {
            int k = tid & 127, hh = (tid >> 7) & 3, tt = (tid >> 9) & 1, i = tid >> 10;
            const float* att = (tt == 0 ? att_src : att_dst) + ((size_t)i * 4 + hh) * 128;
            const float* Wr  = gat_W + ((size_t)i * 128 + k) * 512 + hh * 128;
            float s = 0.f;
            #pragma unroll 8
            for (int c = 0; c < 128; ++c) s = fmaf(Wr[c], att[c], s);
            watt[tid] = s;
        }
    } else {
        // per-(graph,chunk) bucket histogram
        const int blk = b - (PREP_CVX_B + PREP_TRW_B + PREP_WAT_B);
        int g, wg, e0, e1;
        chunk_map(blk, g, wg, e0, e1);
        for (int i = threadIdx.x; i < NBKT; i += 256) h[i] = 0;
        __syncthreads();
        if (g < 5) {
            const int* dsts = scat_idx + (size_t)g * 2 * NE + NE;
            for (int e = e0 + threadIdx.x; e < e1; e += 256)
                atomicAdd(&h[dsts[e] >> 8], 1);
        } else {
            for (int e = e0 + threadIdx.x; e < e1; e += 256) {
                int d = (e < NE) ? edge_ix[NE + e] : (e - NE);
                atomicAdd(&h[d >> 8], 1);
            }
        }
        __syncthreads();
        for (int i = threadIdx.x; i < NBKT; i += 256)
            bh[(size_t)(g * NBKT + i) * NWGMAX + wg] = h[i];
    }
}

// ---------------- bktscan: per-graph bucket totals + exclusive scan -> bucket bases ----------------
__global__ void bktscan(const int* __restrict__ bh, int* __restrict__ bb, int* __restrict__ off6) {
    const int g = blockIdx.x;               // 6
    const int t = threadIdx.x;              // 128
    const int nwg = (g < 5) ? NWG_SET : NWG_GAT;
    __shared__ int s[128];
    int tot = 0;
    if (t < NBKT) {
        const int* p = bh + (size_t)(g * NBKT + t) * NWGMAX;
        for (int w = 0; w < nwg; ++w) tot += p[w];
    }
    s[t] = tot;
    __syncthreads();
    for (int d = 1; d < 128; d <<= 1) {
        int u = (t >= d) ? s[t - d] : 0;
        __syncthreads();
        s[t] += u;
        __syncthreads();
    }
    if (t < NBKT) bb[g * 132 + t] = s[t] - tot;   // exclusive base
    if (t == NBKT - 1) {
        bb[g * 132 + NBKT] = s[t];                // graph total
        off6[g * (NN + 1) + NN] = s[t];
    }
}

// ---------------- wgscan: per-(graph,bucket) exclusive scan over chunks + bucket base ----------------
__global__ void wgscan(const int* __restrict__ bb, int* __restrict__ bh) {
    const int gb = blockIdx.x;                 // 708
    const int g = gb / NBKT, bk = gb - g * NBKT;
    __shared__ int s[128];
    const int t = threadIdx.x;                 // 128
    const int nwg = (g < 5) ? NWG_SET : NWG_GAT;
    int v = (t < nwg) ? bh[(size_t)gb * NWGMAX + t] : 0;
    s[t] = v;
    __syncthreads();
    for (int d = 1; d < 128; d <<= 1) {
        int u = (t >= d) ? s[t - d] : 0;
        __syncthreads();
        s[t] += u;
        __syncthreads();
    }
    const int base = bb[g * 132 + bk];
    if (t < nwg) bh[(size_t)gb * NWGMAX + t] = base + (s[t] - v);
}

// ---------------- binP: write edges into per-(chunk,bucket) windows ----------------
__global__ void __launch_bounds__(256) binP(const int* __restrict__ scat_idx, const float* __restrict__ scat_w,
                                            const int* __restrict__ edge_ix, const int* __restrict__ pos,
                                            int2* __restrict__ stg_sp, int* __restrict__ stg_g) {
    __shared__ int lpos[NBKT];
    __shared__ int lcur[NBKT];
    int g, wg, e0, e1;
    chunk_map(blockIdx.x, g, wg, e0, e1);
    for (int i = threadIdx.x; i < NBKT; i += 256) {
        lpos[i] = pos[(size_t)(g * NBKT + i) * NWGMAX + wg];
        lcur[i] = 0;
    }
    __syncthreads();
    if (g < 5) {
        const int* si = scat_idx + (size_t)g * 2 * NE;
        const float* sw = scat_w + (size_t)g * NE;
        for (int e = e0 + threadIdx.x; e < e1; e += 256) {
            int src = si[e], d = si[NE + e];
            int r = atomicAdd(&lcur[d >> 8], 1);
            int2 pk; pk.x = src | (d << 15); pk.y = __float_as_int(sw[e]);
            stg_sp[(size_t)g * NE + lpos[d >> 8] + r] = pk;
        }
    } else {
        for (int e = e0 + threadIdx.x; e < e1; e += 256) {
            int src, d;
            if (e < NE) { src = edge_ix[e]; d = edge_ix[NE + e]; }
            else        { src = e - NE;     d = src; }
            int r = atomicAdd(&lcur[d >> 8], 1);
            stg_g[lpos[d >> 8] + r] = src | (d << 15);
        }
    }
}

// ---------------- sortP: per-bucket two-pass (count+scan -> off6; scatter) ----------------
__global__ void __launch_bounds__(256) sortP(const int* __restrict__ bb,
                                             const int2* __restrict__ stg_sp, const int* __restrict__ stg_g,
                                             int2* __restrict__ spp, int* __restrict__ g_src,
                                             int* __restrict__ off6) {
    __shared__ int lcnt[256];
    __shared__ int loff[257];
    const int gb = blockIdx.x;
    const int g = gb / NBKT, bk = gb - g * NBKT;
    const int n0 = bk << 8;
    const int nlen = min(256, NN - n0);
    const int base = bb[g * 132 + bk];
    const int end  = bb[g * 132 + bk + 1];
    const int t = threadIdx.x;
    lcnt[t] = 0;
    __syncthreads();
    // pass 1: per-node count (staged data is bucket-local, L2-hot)
    if (g < 5) {
        for (int j = base + t; j < end; j += 256)
            atomicAdd(&lcnt[((stg_sp[(size_t)g * NE + j].x >> 15) & 0x7fff) - n0], 1);
    } else {
        for (int j = base + t; j < end; j += 256)
            atomicAdd(&lcnt[((stg_g[j] >> 15) & 0x7fff) - n0], 1);
    }
    __syncthreads();
    // exclusive scan of 256 counters
    int v = lcnt[t];
    __syncthreads();
    for (int d = 1; d < 256; d <<= 1) {
        int u = (t >= d) ? lcnt[t - d] : 0;
        __syncthreads();
        lcnt[t] += u;
        __syncthreads();
    }
    loff[t] = base + lcnt[t] - v;
    if (t == 255) loff[256] = base + lcnt[255];
    __syncthreads();
    if (t < nlen) off6[g * (NN + 1) + n0 + t] = loff[t];
    lcnt[t] = 0;   // reuse as cursor
    __syncthreads();
    // pass 2: scatter within L2-resident window
    if (g < 5) {
        for (int j = base + t; j < end; j += 256) {
            int2 pk = stg_sp[(size_t)g * NE + j];
            int ln = ((pk.x >> 15) & 0x7fff) - n0;
            int p = loff[ln] + atomicAdd(&lcnt[ln], 1);
            int2 o; o.x = pk.x & 0x7fff; o.y = pk.y;
            spp[(size_t)g * NE + p] = o;
        }
    } else {
        for (int j = base + t; j < end; j += 256) {
            int w = stg_g[j];
            int ln = ((w >> 15) & 0x7fff) - n0;
            int p = loff[ln] + atomicAdd(&lcnt[ln], 1);
            g_src[p] = w & 0x7fff;
        }
    }
}

// ---------------- staging helper for MFMA GEMMs ----------------
template<int ROWS>
__device__ __forceinline__ void stage64(const unsigned short* __restrict__ src, int ld,
                                        int row0, int maxrow, int k0, char* lds, int t) {
    const int wave = t >> 6, lane = t & 63;
    const int sub = lane >> 3;
    const int kch = (lane & 7) ^ sub;
    for (int j = wave; j < ROWS / 8; j += 4) {
        int grow = row0 + j * 8 + sub;
        if (grow > maxrow) grow = maxrow;
        gload_lds16(src + (size_t)grow * ld + k0 + kch * 8, lds + j * 1024);
    }
}

// ---------------- MFMA bf16 GEMM (LIN) ----------------
__global__ void __launch_bounds__(256) mgemm_lin(const unsigned short* __restrict__ A,
                                                 const unsigned short* __restrict__ BT,
                                                 const float* __restrict__ bias,
                                                 unsigned short* __restrict__ outb,
                                                 float* __restrict__ x2) {
    constexpr int K = 512, NC = 128;
    __shared__ __align__(16) char As[64 * 128];
    __shared__ __align__(16) char Bs[128 * 128];
    const int t = threadIdx.x, wave = t >> 6, lane = t & 63;
    const int bm = blockIdx.x * 64;
    const int wr = (wave >> 1) * 32, wc = (wave & 1) * 64;
    const int l15 = lane & 15, l4 = lane >> 4;
    const int rsw = (l15 & 7) << 4;
    f32x4 acc[2][4] = {};

    for (int kt = 0; kt < K; kt += 64) {
        stage64<64>(A, K, bm, NN - 1, kt, As, t);
        stage64<128>(BT, K, 0, NC - 1, kt, Bs, t);
        __syncthreads();
        #pragma unroll
        for (int kk = 0; kk < 2; ++kk) {
            bf16x8 af[2], bf[4];
            const int koff = kk * 64 + l4 * 16;
            #pragma unroll
            for (int fm = 0; fm < 2; ++fm)
                af[fm] = *(const bf16x8*)(As + (wr + fm * 16 + l15) * 128 + (koff ^ rsw));
            #pragma unroll
            for (int fn = 0; fn < 4; ++fn)
                bf[fn] = *(const bf16x8*)(Bs + (wc + fn * 16 + l15) * 128 + (koff ^ rsw));
            #pragma unroll
            for (int fm = 0; fm < 2; ++fm)
                #pragma unroll
                for (int fn = 0; fn < 4; ++fn)
                    acc[fm][fn] = __builtin_amdgcn_mfma_f32_16x16x32_bf16(af[fm], bf[fn], acc[fm][fn], 0, 0, 0);
        }
        __syncthreads();
    }

    #pragma unroll
    for (int fn = 0; fn < 4; ++fn) {
        const int c = wc + fn * 16 + l15;
        const float bias_c = bias[c];
        #pragma unroll
        for (int fm = 0; fm < 2; ++fm) {
            #pragma unroll
            for (int rg = 0; rg < 4; ++rg) {
                int r = bm + wr + fm * 16 + l4 * 4 + rg;
                if (r < NN) {
                    float v = acc[fm][fn][rg] + bias_c;
                    outb[(size_t)r * NC + c] = f2bf(v);
                    x2[(size_t)r * NC + c] = v;
                }
            }
        }
    }
}

// ---------------- fused GATELU + MLP + BN-accumulate ----------------
__global__ void __launch_bounds__(256) fusedGM(const unsigned short* __restrict__ agg,
                                               const unsigned short* __restrict__ gatWT,
                                               const unsigned short* __restrict__ mlpWT,
                                               const float* __restrict__ gat_b,
                                               const float* __restrict__ mlp_b,
                                               const float* __restrict__ bng, const float* __restrict__ bnb,
                                               const float* __restrict__ bnm, const float* __restrict__ bnv,
                                               float* __restrict__ x2) {
    __shared__ __align__(16) char U[49152];
    __shared__ __align__(16) char gtile[16384];
    const int t = threadIdx.x, wave = t >> 6, lane = t & 63;
    const int bm = blockIdx.x * 64;
    const int wr = (wave >> 1) * 32, wc = (wave & 1) * 64;
    const int l15 = lane & 15, l4 = lane >> 4;
    const int rsw = (l15 & 7) << 4;
    f32x4 acc2[2][4] = {};

    #pragma unroll
    for (int h = 0; h < 4; ++h) {
        stage64<64>(agg, 512, bm, NN - 1, h * 128,       U,         t);
        stage64<64>(agg, 512, bm, NN - 1, h * 128 + 64,  U + 8192,  t);
        stage64<128>(gatWT, 128, h * 128, 511, 0,        U + 16384, t);
        stage64<128>(gatWT, 128, h * 128, 511, 64,       U + 32768, t);
        __syncthreads();

        f32x4 a1[2][4] = {};
        #pragma unroll
        for (int ks = 0; ks < 4; ++ks) {
            const char* Asb = U + (ks >> 1) * 8192;
            const char* Bsb = U + 16384 + (ks >> 1) * 16384;
            const int koff = (ks & 1) * 64 + l4 * 16;
            bf16x8 af[2], bf[4];
            #pragma unroll
            for (int fm = 0; fm < 2; ++fm)
                af[fm] = *(const bf16x8*)(Asb + (wr + fm * 16 + l15) * 128 + (koff ^ rsw));
            #pragma unroll
            for (int fn = 0; fn < 4; ++fn)
                bf[fn] = *(const bf16x8*)(Bsb + (wc + fn * 16 + l15) * 128 + (koff ^ rsw));
            #pragma unroll
            for (int fm = 0; fm < 2; ++fm)
                #pragma unroll
                for (int fn = 0; fn < 4; ++fn)
                    a1[fm][fn] = __builtin_amdgcn_mfma_f32_16x16x32_bf16(af[fm], bf[fn], a1[fm][fn], 0, 0, 0);
        }
        __syncthreads();

        #pragma unroll
        for (int fn = 0; fn < 4; ++fn) {
            const int cc = wc + fn * 16 + l15;
            const float gb = gat_b[h * 128 + cc];
            #pragma unroll
            for (int fm = 0; fm < 2; ++fm) {
                #pragma unroll
                for (int rg = 0; rg < 4; ++rg) {
                    const int r = wr + fm * 16 + l4 * 4 + rg;
                    const unsigned short v = f2bf(eluf(a1[fm][fn][rg] + gb));
                    *(unsigned short*)(gtile + r * 256 + ((((cc >> 3) ^ (r & 7)) << 4) | ((cc & 7) << 1))) = v;
                }
            }
        }
        stage64<128>(mlpWT, 512, 0, 127, h * 128,      U,         t);
        stage64<128>(mlpWT, 512, 0, 127, h * 128 + 64, U + 16384, t);
        __syncthreads();

        #pragma unroll
        for (int ks = 0; ks < 4; ++ks) {
            const int s2 = ks >> 1, kk = ks & 1;
            const char* slab = U + s2 * 16384;
            bf16x8 af[2], bf[4];
            #pragma unroll
            for (int fm = 0; fm < 2; ++fm) {
                const int r2 = wr + fm * 16 + l15;
                const int chunk = (s2 * 8 + kk * 4 + l4) ^ (r2 & 7);
                af[fm] = *(const bf16x8*)(gtile + r2 * 256 + (chunk << 4));
            }
            const int koff = kk * 64 + l4 * 16;
            #pragma unroll
            for (int fn = 0; fn < 4; ++fn)
                bf[fn] = *(const bf16x8*)(slab + (wc + fn * 16 + l15) * 128 + (koff ^ rsw));
            #pragma unroll
            for (int fm = 0; fm < 2; ++fm)
                #pragma unroll
                for (int fn = 0; fn < 4; ++fn)
                    acc2[fm][fn] = __builtin_amdgcn_mfma_f32_16x16x32_bf16(af[fm], bf[fn], acc2[fm][fn], 0, 0, 0);
        }
        __syncthreads();
    }

    #pragma unroll
    for (int fn = 0; fn < 4; ++fn) {
        const int c = wc + fn * 16 + l15;
        const float sc = bng[c] * rsqrtf(bnv[c] + BN_EPS);
        const float sh = bnb[c] - bnm[c] * sc;
        const float mb = mlp_b[c];
        #pragma unroll
        for (int fm = 0; fm < 2; ++fm) {
            #pragma unroll
            for (int rg = 0; rg < 4; ++rg) {
                int r = bm + wr + fm * 16 + l4 * 4 + rg;
                if (r < NN)
                    x2[(size_t)r * 128 + c] += (acc2[fm][fn][rg] + mb) * sc + sh;
            }
        }
    }
}

// ---------------- phase 0: tmp_y = abs(sp(y+1, hb)), 8-way edge unroll ----------------
__global__ void __launch_bounds__(256) sp_abs4(const int* __restrict__ off6,
                                               const int2* __restrict__ spp,
                                               const unsigned short* __restrict__ hb,
                                               unsigned short* __restrict__ tmp4) {
    const int y = blockIdx.y;
    const int* off = off6 + (y + 1) * (NN + 1);
    const int2* pk = spp + (size_t)(y + 1) * NE;
    unsigned short* out = tmp4 + (size_t)y * NN * 128;

    const int wid  = blockIdx.x * 4 + (threadIdx.x >> 6);
    const int lane = threadIdx.x & 63;
    const int co   = lane * 2;
    const int s0 = off[wid], s1 = off[wid + 1];
    float a0 = 0.f, a1 = 0.f;
    int j = s0;
    for (; j + 7 < s1; j += 8) {
        int2 e[8];
        unsigned v[8];
        #pragma unroll
        for (int q = 0; q < 8; ++q) e[q] = pk[j + q];
        #pragma unroll
        for (int q = 0; q < 8; ++q) v[q] = *(const unsigned*)(hb + (size_t)e[q].x * 128 + co);
        #pragma unroll
        for (int q = 0; q < 8; ++q) {
            float w = __int_as_float(e[q].y);
            a0 = fmaf(w, bf2f(v[q] & 0xffffu), a0);
            a1 = fmaf(w, bf2f(v[q] >> 16), a1);
        }
    }
    for (; j < s1; ++j) {
        int2 e = pk[j];
        float wj = __int_as_float(e.y);
        unsigned v = *(const unsigned*)(hb + (size_t)e.x * 128 + co);
        a0 = fmaf(wj, bf2f(v & 0xffffu), a0);
        a1 = fmaf(wj, bf2f(v >> 16), a1);
    }
    a0 = fabsf(a0); a1 = fabsf(a1);
    unsigned o = (unsigned)f2bf(a0) | ((unsigned)f2bf(a1) << 16);
    *(unsigned*)(out + (size_t)wid * 128 + co) = o;
}

// ---------------- phase 1: xcur_y = sp(0, {hb,tmp0..3}) fused + attention scores ----------------
__global__ void __launch_bounds__(256) sp_fused5(const int* __restrict__ off0,
                                                 const int2* __restrict__ spp0,
                                                 const unsigned short* __restrict__ hb,
                                                 const unsigned short* __restrict__ tmp4,
                                                 unsigned short* __restrict__ xcur5,
                                                 const float* __restrict__ watt,
                                                 float* __restrict__ as5,
                                                 float* __restrict__ ad5) {
    __shared__ float sWatt[5120];
    for (int i = threadIdx.x; i < 5120; i += 256) sWatt[i] = watt[i];
    __syncthreads();

    const int wid  = blockIdx.x * 4 + (threadIdx.x >> 6);
    const int lane = threadIdx.x & 63;
    const int co   = lane * 2;
    const int s0 = off0[wid], s1 = off0[wid + 1];
    const unsigned short* t0 = tmp4;
    const unsigned short* t1 = tmp4 + (size_t)1 * NN * 128;
    const unsigned short* t2 = tmp4 + (size_t)2 * NN * 128;
    const unsigned short* t3 = tmp4 + (size_t)3 * NN * 128;

    float a[5][2] = {};
    int j = s0;
    for (; j + 1 < s1; j += 2) {
        int2 eA = spp0[j], eB = spp0[j + 1];
        size_t rA = (size_t)eA.x * 128 + co, rB = (size_t)eB.x * 128 + co;
        unsigned vA0 = *(const unsigned*)(hb + rA), vB0 = *(const unsigned*)(hb + rB);
        unsigned vA1 = *(const unsigned*)(t0 + rA), vB1 = *(const unsigned*)(t0 + rB);
        unsigned vA2 = *(const unsigned*)(t1 + rA), vB2 = *(const unsigned*)(t1 + rB);
        unsigned vA3 = *(const unsigned*)(t2 + rA), vB3 = *(const unsigned*)(t2 + rB);
        unsigned vA4 = *(const unsigned*)(t3 + rA), vB4 = *(const unsigned*)(t3 + rB);
        float wA = __int_as_float(eA.y), wB = __int_as_float(eB.y);
        a[0][0] = fmaf(wA, bf2f(vA0 & 0xffffu), a[0][0]); a[0][1] = fmaf(wA, bf2f(vA0 >> 16), a[0][1]);
        a[1][0] = fmaf(wA, bf2f(vA1 & 0xffffu), a[1][0]); a[1][1] = fmaf(wA, bf2f(vA1 >> 16), a[1][1]);
        a[2][0] = fmaf(wA, bf2f(vA2 & 0xffffu), a[2][0]); a[2][1] = fmaf(wA, bf2f(vA2 >> 16), a[2][1]);
        a[3][0] = fmaf(wA, bf2f(vA3 & 0xffffu), a[3][0]); a[3][1] = fmaf(wA, bf2f(vA3 >> 16), a[3][1]);
        a[4][0] = fmaf(wA, bf2f(vA4 & 0xffffu), a[4][0]); a[4][1] = fmaf(wA, bf2f(vA4 >> 16), a[4][1]);
        a[0][0] = fmaf(wB, bf2f(vB0 & 0xffffu), a[0][0]); a[0][1] = fmaf(wB, bf2f(vB0 >> 16), a[0][1]);
        a[1][0] = fmaf(wB, bf2f(vB1 & 0xffffu), a[1][0]); a[1][1] = fmaf(wB, bf2f(vB1 >> 16), a[1][1]);
        a[2][0] = fmaf(wB, bf2f(vB2 & 0xffffu), a[2][0]); a[2][1] = fmaf(wB, bf2f(vB2 >> 16), a[2][1]);
        a[3][0] = fmaf(wB, bf2f(vB3 & 0xffffu), a[3][0]); a[3][1] = fmaf(wB, bf2f(vB3 >> 16), a[3][1]);
        a[4][0] = fmaf(wB, bf2f(vB4 & 0xffffu), a[4][0]); a[4][1] = fmaf(wB, bf2f(vB4 >> 16), a[4][1]);
    }
    if (j < s1) {
        int2 e = spp0[j];
        size_t r = (size_t)e.x * 128 + co;
        unsigned v0 = *(const unsigned*)(hb + r);
        unsigned v1 = *(const unsigned*)(t0 + r);
        unsigned v2 = *(const unsigned*)(t1 + r);
        unsigned v3 = *(const unsigned*)(t2 + r);
        unsigned v4 = *(const unsigned*)(t3 + r);
        float wj = __int_as_float(e.y);
        a[0][0] = fmaf(wj, bf2f(v0 & 0xffffu), a[0][0]); a[0][1] = fmaf(wj, bf2f(v0 >> 16), a[0][1]);
        a[1][0] = fmaf(wj, bf2f(v1 & 0xffffu), a[1][0]); a[1][1] = fmaf(wj, bf2f(v1 >> 16), a[1][1]);
        a[2][0] = fmaf(wj, bf2f(v2 & 0xffffu), a[2][0]); a[2][1] = fmaf(wj, bf2f(v2 >> 16), a[2][1]);
        a[3][0] = fmaf(wj, bf2f(v3 & 0xffffu), a[3][0]); a[3][1] = fmaf(wj, bf2f(v3 >> 16), a[3][1]);
        a[4][0] = fmaf(wj, bf2f(v4 & 0xffffu), a[4][0]); a[4][1] = fmaf(wj, bf2f(v4 >> 16), a[4][1]);
    }
    #pragma unroll
    for (int y = 0; y < 5; ++y) {
        unsigned o = (unsigned)f2bf(a[y][0]) | ((unsigned)f2bf(a[y][1]) << 16);
        *(unsigned*)(xcur5 + (size_t)y * NN * 128 + (size_t)wid * 128 + co) = o;
    }

    #pragma unroll
    for (int i = 0; i < 5; ++i) {
        #pragma unroll
        for (int h = 0; h < 4; ++h) {
            const float* wS = sWatt + ((i * 2 + 0) * 4 + h) * 128;
            const float* wD = sWatt + ((i * 2 + 1) * 4 + h) * 128;
            float ps = a[i][0] * wS[co] + a[i][1] * wS[co + 1];
            float pd = a[i][0] * wD[co] + a[i][1] * wD[co + 1];
            #pragma unroll
            for (int dd = 1; dd < 64; dd <<= 1) { ps += __shfl_xor(ps, dd); pd += __shfl_xor(pd, dd); }
            if (lane == 0) {
                as5[(size_t)i * NN * 4 + (size_t)wid * 4 + h] = ps;
                ad5[(size_t)i * NN * 4 + (size_t)wid * 4 + h] = pd;
            }
        }
    }
}

// ---------------- GAT aggregation on xcur (pre-W) ----------------
__device__ __forceinline__ void acc8(float* a, float al, uint4 v) {
    a[0] = fmaf(al, bf2f(v.x & 0xffffu), a[0]); a[1] = fmaf(al, bf2f(v.x >> 16), a[1]);
    a[2] = fmaf(al, bf2f(v.y & 0xffffu), a[2]); a[3] = fmaf(al, bf2f(v.y >> 16), a[3]);
    a[4] = fmaf(al, bf2f(v.z & 0xffffu), a[4]); a[5] = fmaf(al, bf2f(v.z >> 16), a[5]);
    a[6] = fmaf(al, bf2f(v.w & 0xffffu), a[6]); a[7] = fmaf(al, bf2f(v.w >> 16), a[7]);
}

__global__ void __launch_bounds__(256) gat_agg2(const int* __restrict__ goff, const int* __restrict__ gsrc,
                                                const float* __restrict__ as_, const float* __restrict__ ad_,
                                                const unsigned short* __restrict__ xcur,
                                                unsigned short* __restrict__ agg) {
    const int wid  = blockIdx.x * 4 + (threadIdx.x >> 6);
    const int lane = threadIdx.x & 63;
    const int hd   = lane >> 4;
    const int cl   = (lane & 15) * 8;
    const int s0 = goff[wid], s1 = goff[wid + 1];
    const float4 adv4 = *(const float4*)(ad_ + (size_t)wid * 4);

    float m[4] = {-1e30f, -1e30f, -1e30f, -1e30f};
    float s[4] = {0.f, 0.f, 0.f, 0.f};
    for (int j = s0 + lane; j < s1; j += 64) {
        const int si = gsrc[j];
        float4 av = *(const float4*)(as_ + (size_t)si * 4);
        float e[4] = {lrelu02(av.x + adv4.x), lrelu02(av.y + adv4.y),
                      lrelu02(av.z + adv4.z), lrelu02(av.w + adv4.w)};
        #pragma unroll
        for (int h = 0; h < 4; ++h) {
            if (e[h] > m[h]) { s[h] = s[h] * __expf(m[h] - e[h]) + 1.f; m[h] = e[h]; }
            else             { s[h] += __expf(e[h] - m[h]); }
        }
    }
    #pragma unroll
    for (int d = 1; d < 64; d <<= 1) {
        #pragma unroll
        for (int h = 0; h < 4; ++h) {
            float om = __shfl_xor(m[h], d);
            float os = __shfl_xor(s[h], d);
            float nm = fmaxf(m[h], om);
            s[h] = s[h] * __expf(m[h] - nm) + os * __expf(om - nm);
            m[h] = nm;
        }
    }
    const float advh = hd == 0 ? adv4.x : hd == 1 ? adv4.y : hd == 2 ? adv4.z : adv4.w;
    const float mv   = hd == 0 ? m[0]   : hd == 1 ? m[1]   : hd == 2 ? m[2]   : m[3];
    const float dv   = hd == 0 ? s[0]   : hd == 1 ? s[1]   : hd == 2 ? s[2]   : s[3];
    const float inv  = 1.f / (dv + 1e-16f);

    float ac[8] = {};
    int j = s0;
    for (; j + 3 < s1; j += 4) {
        int i0 = gsrc[j], i1 = gsrc[j + 1], i2 = gsrc[j + 2], i3 = gsrc[j + 3];
        float q0 = as_[(size_t)i0 * 4 + hd], q1 = as_[(size_t)i1 * 4 + hd];
        float q2 = as_[(size_t)i2 * 4 + hd], q3 = as_[(size_t)i3 * 4 + hd];
        uint4 v0 = *(const uint4*)(xcur + (size_t)i0 * 128 + cl);
        uint4 v1 = *(const uint4*)(xcur + (size_t)i1 * 128 + cl);
        uint4 v2 = *(const uint4*)(xcur + (size_t)i2 * 128 + cl);
        uint4 v3 = *(const uint4*)(xcur + (size_t)i3 * 128 + cl);
        float al0 = __expf(lrelu02(q0 + advh) - mv) * inv;
        float al1 = __expf(lrelu02(q1 + advh) - mv) * inv;
        float al2 = __expf(lrelu02(q2 + advh) - mv) * inv;
        float al3 = __expf(lrelu02(q3 + advh) - mv) * inv;
        acc8(ac, al0, v0); acc8(ac, al1, v1); acc8(ac, al2, v2); acc8(ac, al3, v3);
    }
    for (; j < s1; ++j) {
        int si = gsrc[j];
        float q = as_[(size_t)si * 4 + hd];
        uint4 v = *(const uint4*)(xcur + (size_t)si * 128 + cl);
        float al = __expf(lrelu02(q + advh) - mv) * inv;
        acc8(ac, al, v);
    }
    uint4 ov;
    ov.x = (unsigned)f2bf(ac[0]) | ((unsigned)f2bf(ac[1]) << 16);
    ov.y = (unsigned)f2bf(ac[2]) | ((unsigned)f2bf(ac[3]) << 16);
    ov.z = (unsigned)f2bf(ac[4]) | ((unsigned)f2bf(ac[5]) << 16);
    ov.w = (unsigned)f2bf(ac[6]) | ((unsigned)f2bf(ac[7]) << 16);
    *(uint4*)(agg + (size_t)wid * 512 + hd * 128 + cl) = ov;
}

// ---------------- final ----------------
__global__ void __launch_bounds__(256) final_out(const float* __restrict__ x2,
                                                 const float* __restrict__ bn0g, const float* __restrict__ bn0b,
                                                 const float* __restrict__ bn0m, const float* __restrict__ bn0v,
                                                 const float* __restrict__ outW, const float* __restrict__ outb,
                                                 float* __restrict__ out) {
    __shared__ float sW[128 * 12];
    __shared__ float sSc[128], sSh[128];
    for (int i = threadIdx.x; i < 1280; i += 256) {
        int r = i / 10, c = i - r * 10;
        sW[r * 12 + c] = outW[i];
    }
    if (threadIdx.x < 128) {
        int c = threadIdx.x;
        float sc = bn0g[c] * rsqrtf(bn0v[c] + BN_EPS);
        sSc[c] = sc;
        sSh[c] = bn0b[c] - bn0m[c] * sc;
    }
    __syncthreads();
    const int wid  = blockIdx.x * 4 + (threadIdx.x >> 6);
    const int lane = threadIdx.x & 63;
    const int c0 = lane * 2;
    float2 a = *(const float2*)(x2 + (size_t)wid * 128 + c0);
    float a0 = eluf(a.x * sSc[c0] + sSh[c0]);
    float a1 = eluf(a.y * sSc[c0 + 1] + sSh[c0 + 1]);
    float p[NCLS];
    #pragma unroll
    for (int j = 0; j < NCLS; ++j)
        p[j] = a0 * sW[c0 * 12 + j] + a1 * sW[(c0 + 1) * 12 + j];
    #pragma unroll
    for (int j = 0; j < NCLS; ++j) {
        float v = p[j];
        v += __shfl_xor(v, 1);  v += __shfl_xor(v, 2);  v += __shfl_xor(v, 4);
        v += __shfl_xor(v, 8);  v += __shfl_xor(v, 16); v += __shfl_xor(v, 32);
        p[j] = v;
    }
    float z[NCLS];
    #pragma unroll
    for (int j = 0; j < NCLS; ++j) z[j] = p[j] + outb[j];
    float m = z[0];
    #pragma unroll
    for (int j = 1; j < NCLS; ++j) m = fmaxf(m, z[j]);
    float ssum = 0.f;
    #pragma unroll
    for (int j = 0; j < NCLS; ++j) ssum += __expf(z[j] - m);
    float lse = m + __logf(ssum);
    #pragma unroll
    for (int j = 0; j < NCLS; ++j)
        if (lane == j) out[(size_t)wid * NCLS + j] = z[j] - lse;
}

// ---------------- launcher ----------------
extern "C" void kernel_launch(void* const* d_in, const int* in_sizes, int n_in,
                              void* d_out, int out_size, void* d_ws, size_t ws_size,
                              hipStream_t stream) {
    const float* x        = (const float*)d_in[0];
    const int*   edge_ix  = (const int*)  d_in[1];
    const int*   scat_idx = (const int*)  d_in[2];
    const float* scat_w   = (const float*)d_in[3];
    const float* lin_W    = (const float*)d_in[4];
    const float* lin_b    = (const float*)d_in[5];
    const float* gat_W    = (const float*)d_in[6];
    const float* att_src  = (const float*)d_in[7];
    const float* att_dst  = (const float*)d_in[8];
    const float* gat_b    = (const float*)d_in[9];
    const float* mlp_W    = (const float*)d_in[10];
    const float* mlp_b    = (const float*)d_in[11];
    const float* bn_g     = (const float*)d_in[12];
    const float* bn_b     = (const float*)d_in[13];
    const float* bn_m     = (const float*)d_in[14];
    const float* bn_v     = (const float*)d_in[15];
    const float* bn0_g    = (const float*)d_in[16];
    const float* bn0_b    = (const float*)d_in[17];
    const float* bn0_m    = (const float*)d_in[18];
    const float* bn0_v    = (const float*)d_in[19];
    const float* out_W    = (const float*)d_in[20];
    const float* out_b    = (const float*)d_in[21];
    float* out = (float*)d_out;

    char* ws = (char*)d_ws;
    unsigned short* xb    = (unsigned short*)(ws + OFF_U1);
    unsigned short* xcur5 = (unsigned short*)(ws + OFF_U1);
    unsigned short* hb    = (unsigned short*)(ws + OFF_HB);
    float*          x2    = (float*)(ws + OFF_X2);
    unsigned short* agg   = (unsigned short*)(ws + OFF_AGG);
    unsigned short* tmp4  = (unsigned short*)(ws + OFF_GOUT);
    int2*  stg_sp = (int2*)(ws + OFF_GOUT);                           // staging (dead before tmp4 use)
    int*   stg_g  = (int*)(ws + OFF_GOUT + (size_t)NSETS * NE * 8);
    unsigned short* wt    = (unsigned short*)(ws + OFF_WT);
    unsigned short* linWT = wt;
    unsigned short* gatWT = wt + 65536;
    unsigned short* mlpWT = wt + 65536 * 6;
    float* watt   = (float*)(ws + OFF_WATT);
    int*   off6   = (int*)(ws + OFF_OFF6);
    int2*  spp    = (int2*)(ws + OFF_SPP);
    int*   g_src  = (int*)(ws + OFF_GSRC);
    int*   bh     = (int*)(ws + OFF_CNT);               // [708][105] chunk histograms / positions
    int*   bb     = bh + NBLK_SORT * NWGMAX;            // [6][132] bucket bases + totals
    float* as5    = (float*)(ws + OFF_AS5);
    float* ad5    = (float*)(ws + OFF_AD5);

    const dim3 b256(256);

    // ---- CSR build: hist(prep1) -> bucket scan -> chunk scan -> bin -> bucket sort (writes off6) ----
    prep1<<<PREP_GRID, b256, 0, stream>>>(scat_idx, edge_ix, bh, x, xb,
                                          lin_W, gat_W, mlp_W, linWT, gatWT, mlpWT,
                                          att_src, att_dst, watt);
    bktscan<<<6, 128, 0, stream>>>(bh, bb, off6);
    wgscan<<<NBLK_SORT, 128, 0, stream>>>(bb, bh);
    binP<<<NBLK_BIN, b256, 0, stream>>>(scat_idx, scat_w, edge_ix, bh, stg_sp, stg_g);
    sortP<<<NBLK_SORT, b256, 0, stream>>>(bb, stg_sp, stg_g, spp, g_src, off6);

    // ---- h = x @ lin_W + lin_b ; x2 = h ----
    mgemm_lin<<<469, b256, 0, stream>>>(xb, linWT, lin_b, hb, x2);

    // ---- solo passes (+ fused attention scores) ----
    sp_abs4<<<dim3(7500, 4), b256, 0, stream>>>(off6, spp, hb, tmp4);
    sp_fused5<<<7500, b256, 0, stream>>>(off6, spp, hb, tmp4, xcur5, watt, as5, ad5);

    // ---- 5 GAT branches ----
    for (int i = 0; i < NSETS; ++i) {
        gat_agg2<<<7500, b256, 0, stream>>>(off6 + 5 * (NN + 1), g_src,
                                            as5 + (size_t)i * NN * 4, ad5 + (size_t)i * NN * 4,
                                            xcur5 + (size_t)i * NN * 128, agg);
        fusedGM<<<469, b256, 0, stream>>>(agg, gatWT + (size_t)i * 65536, mlpWT + (size_t)i * 65536,
                                          gat_b + (size_t)i * 512, mlp_b + (size_t)i * 128,
                                          bn_g + (size_t)i * 128, bn_b + (size_t)i * 128,
                                          bn_m + (size_t)i * 128, bn_v + (size_t)i * 128, x2);
    }

    // ---- final ----
    final_out<<<7500, b256, 0, stream>>>(x2, bn0_g, bn0_b, bn0_m, bn0_v, out_W, out_b, out);
}